// Round 9
// baseline (91.640 us; speedup 1.0000x reference)
//
#include <hip/hip_runtime.h>
#include <stdint.h>

typedef float f32x4 __attribute__((ext_vector_type(4)));
typedef float f32x16 __attribute__((ext_vector_type(16)));
typedef __bf16 bf16x8 __attribute__((ext_vector_type(8)));
typedef unsigned int uint2v __attribute__((ext_vector_type(2)));

#define MFMA16(a,b,c) __builtin_amdgcn_mfma_f32_16x16x32_bf16((a),(b),(c),0,0,0)
#define MFMA32(a,b,c) __builtin_amdgcn_mfma_f32_32x32x16_bf16((a),(b),(c),0,0,0)

__device__ __forceinline__ unsigned short f2bf(float f){
  unsigned int u = __float_as_uint(f);
  u += 0x7FFFu + ((u >> 16) & 1u);
  return (unsigned short)(u >> 16);
}

__device__ __forceinline__ unsigned cvtpk(float lo, float hi){
  unsigned r;
  asm volatile("v_cvt_pk_bf16_f32 %0, %1, %2" : "=v"(r) : "v"(lo), "v"(hi));
  return r;
}

__device__ __forceinline__ float fexp2(float x){
#if __has_builtin(__builtin_amdgcn_exp2f)
  return __builtin_amdgcn_exp2f(x);
#else
  return exp2f(x);
#endif
}

__device__ __forceinline__ void plswap(unsigned &a, unsigned &b){
#if __has_builtin(__builtin_amdgcn_permlane32_swap)
  uint2v r = __builtin_amdgcn_permlane32_swap(a, b, false, false);
  a = r[0]; b = r[1];
#else
  unsigned xa = __shfl_xor(a, 32), xb = __shfl_xor(b, 32);
  int hi = (threadIdx.x & 63) >> 5;
  unsigned na = hi ? xb : a;
  unsigned nb = hi ? b : xa;
  a = na; b = nb;
#endif
}

// async global -> LDS, 16B per lane; LDS dest is wave-uniform base + lane*16
__device__ __forceinline__ void stage16(const unsigned short* g, unsigned short* l){
  __builtin_amdgcn_global_load_lds(
      (const __attribute__((address_space(1))) void*)g,
      (__attribute__((address_space(3))) void*)l, 16, 0, 0);
}

// ---------------- prep router: weight transposes + LN(x) + cast(ctx) + maskbits ----------------
__global__ __launch_bounds__(256) void k_prep(
    const float* __restrict__ Wq, const float* __restrict__ Wkv, const float* __restrict__ Wo,
    const float* __restrict__ x, const float* __restrict__ ln_g, const float* __restrict__ ln_b,
    const float* __restrict__ ctx, const int* __restrict__ mask,
    unsigned short* __restrict__ WqT, unsigned short* __restrict__ WkvT, unsigned short* __restrict__ WoT,
    unsigned short* __restrict__ xn, unsigned short* __restrict__ cb, unsigned int* __restrict__ mb)
{
  __shared__ float tile[32][33];
  const int bid = blockIdx.x, t = threadIdx.x;
  if (bid < 1024) {
    const float* W; unsigned short* WT; int N, bx, by;
    if (bid < 256)      { W = Wq;  WT = WqT;  N = 512;  bx = bid & 15;        by = bid >> 4; }
    else if (bid < 768) { W = Wkv; WT = WkvT; N = 1024; bx = (bid-256) & 31;  by = (bid-256) >> 5; }
    else                { W = Wo;  WT = WoT;  N = 512;  bx = (bid-768) & 15;  by = (bid-768) >> 4; }
    const int tx = t & 31, ty = t >> 5;
    #pragma unroll
    for (int i = 0; i < 4; i++)
      tile[ty + i*8][tx] = W[(size_t)(by*32 + ty + i*8) * N + bx*32 + tx];
    __syncthreads();
    #pragma unroll
    for (int i = 0; i < 4; i++)
      WT[(size_t)(bx*32 + ty + i*8) * 512 + by*32 + tx] = f2bf(tile[tx][ty + i*8]);
  } else if (bid < 2048) {
    int row = (bid - 1024) * 4 + (t >> 6);
    int lane = t & 63;
    const float4* xr = (const float4*)(x + (size_t)row * 512);
    float4 a = xr[lane], c = xr[64 + lane];
    float s = a.x + a.y + a.z + a.w + c.x + c.y + c.z + c.w;
    #pragma unroll
    for (int o = 32; o; o >>= 1) s += __shfl_xor(s, o);
    float mu = s * (1.0f / 512.0f);
    float va = (a.x-mu)*(a.x-mu) + (a.y-mu)*(a.y-mu) + (a.z-mu)*(a.z-mu) + (a.w-mu)*(a.w-mu)
             + (c.x-mu)*(c.x-mu) + (c.y-mu)*(c.y-mu) + (c.z-mu)*(c.z-mu) + (c.w-mu)*(c.w-mu);
    #pragma unroll
    for (int o = 32; o; o >>= 1) va += __shfl_xor(va, o);
    float inv = rsqrtf(va * (1.0f / 512.0f) + 1e-5f);
    const float4* gp = (const float4*)ln_g;
    const float4* bp = (const float4*)ln_b;
    float4 g0 = gp[lane], g1 = gp[64 + lane], b0 = bp[lane], b1 = bp[64 + lane];
    ushort4* op = (ushort4*)(xn + (size_t)row * 512);
    op[lane]      = make_ushort4(f2bf((a.x-mu)*inv*g0.x + b0.x), f2bf((a.y-mu)*inv*g0.y + b0.y),
                                 f2bf((a.z-mu)*inv*g0.z + b0.z), f2bf((a.w-mu)*inv*g0.w + b0.w));
    op[64 + lane] = make_ushort4(f2bf((c.x-mu)*inv*g1.x + b1.x), f2bf((c.y-mu)*inv*g1.y + b1.y),
                                 f2bf((c.z-mu)*inv*g1.z + b1.z), f2bf((c.w-mu)*inv*g1.w + b1.w));
  } else if (bid < 4096) {
    int i = (bid - 2048) * 256 + t;
    float4 v = ((const float4*)ctx)[i];
    ((ushort4*)cb)[i] = make_ushort4(f2bf(v.x), f2bf(v.y), f2bf(v.z), f2bf(v.w));
  } else {
    int g = (bid - 4096) * 4 + (t >> 6);
    int ln = t & 63;
    int v = mask[g * 64 + ln];
    unsigned long long bb = __ballot(v != 0);
    if (ln == 0) { mb[g*2] = (unsigned)bb; mb[g*2+1] = (unsigned)(bb >> 32); }
  }
}

// ---------------- final layernorm (f32 in/out) ----------------
__global__ __launch_bounds__(256) void k_layernorm_f(
    const float* __restrict__ X, const float* __restrict__ G,
    const float* __restrict__ Bt, float* __restrict__ out)
{
  int row = blockIdx.x * 4 + (threadIdx.x >> 6);
  int lane = threadIdx.x & 63;
  const float4* xr = (const float4*)(X + (size_t)row * 512);
  float4 a = xr[lane], c = xr[64 + lane];
  float s = a.x + a.y + a.z + a.w + c.x + c.y + c.z + c.w;
  #pragma unroll
  for (int o = 32; o; o >>= 1) s += __shfl_xor(s, o);
  float mu = s * (1.0f / 512.0f);
  float va = (a.x-mu)*(a.x-mu) + (a.y-mu)*(a.y-mu) + (a.z-mu)*(a.z-mu) + (a.w-mu)*(a.w-mu)
           + (c.x-mu)*(c.x-mu) + (c.y-mu)*(c.y-mu) + (c.z-mu)*(c.z-mu) + (c.w-mu)*(c.w-mu);
  #pragma unroll
  for (int o = 32; o; o >>= 1) va += __shfl_xor(va, o);
  float inv = rsqrtf(va * (1.0f / 512.0f) + 1e-5f);
  const float4* gp = (const float4*)G;
  const float4* bp = (const float4*)Bt;
  float4 g0 = gp[lane], g1 = gp[64 + lane], b0 = bp[lane], b1 = bp[64 + lane];
  float4 y0, y1;
  y0.x = (a.x-mu)*inv*g0.x + b0.x; y0.y = (a.y-mu)*inv*g0.y + b0.y;
  y0.z = (a.z-mu)*inv*g0.z + b0.z; y0.w = (a.w-mu)*inv*g0.w + b0.w;
  y1.x = (c.x-mu)*inv*g1.x + b1.x; y1.y = (c.y-mu)*inv*g1.y + b1.y;
  y1.z = (c.z-mu)*inv*g1.z + b1.z; y1.w = (c.w-mu)*inv*g1.w + b1.w;
  float4* op = (float4*)(out + (size_t)row * 512);
  op[lane] = y0; op[64 + lane] = y1;
}

// ---------------- bf16 MFMA GEMM body: 64x128 tile, BK=64, 4 waves (2x2) ----------------
// Staging via global_load_lds (async DMA, no staging VGPRs), double-buffered LDS,
// one __syncthreads per K-step. Swizzle applied on the GLOBAL source address;
// LDS dest linear per wave (wave-uniform base + lane*16B).
// MODE 0: fragment-packed Q out. MODE 1: KV -> packed Kp (col<512) / Vp. MODE 2: f32 out.
template<int MODE>
__device__ __forceinline__ void gemm_body(
    const unsigned short* __restrict__ A, const unsigned short* __restrict__ BT,
    void* __restrict__ out0, void* __restrict__ out1, int bx, int by,
    unsigned short* smem)
{
  unsigned short* As = smem;              // [2][64*64]  = 16 KB
  unsigned short* Bs = smem + 2*64*64;    // [2][128*64] = 32 KB
  const int t = threadIdx.x;
  const int lane = t & 63, l16 = lane & 15, lhi = lane >> 4;
  const int w = t >> 6, wm = w >> 1, wn = w & 1;
  const int rowBase = by * 64;
  const int colBase = bx * 128;
  const int srr = lane >> 3, scw = lane & 7;

  f32x4 acc[2][4];
  #pragma unroll
  for (int i = 0; i < 2; i++)
    #pragma unroll
    for (int j = 0; j < 4; j++)
      acc[i][j] = f32x4{0.f, 0.f, 0.f, 0.f};

  auto STAGE = [&](int buf, int kt) {
    unsigned short* Ab = As + buf * 4096;
    unsigned short* Bb = Bs + buf * 8192;
    #pragma unroll
    for (int i = 0; i < 2; i++) {
      int rr = i * 32 + w * 8 + srr;
      stage16(A + (size_t)(rowBase + rr) * 512 + kt * 64 + ((scw ^ (rr & 7)) * 8),
              Ab + (i * 32 + w * 8) * 64);
    }
    #pragma unroll
    for (int i = 0; i < 4; i++) {
      int rr = i * 32 + w * 8 + srr;
      stage16(BT + (size_t)(colBase + rr) * 512 + kt * 64 + ((scw ^ (rr & 7)) * 8),
              Bb + (i * 32 + w * 8) * 64);
    }
  };

  STAGE(0, 0);
  __syncthreads();                         // vmcnt(0) drain + barrier: buf0 ready
  for (int kt = 0; kt < 8; ++kt) {
    const int buf = kt & 1;
    if (kt < 7) STAGE(buf ^ 1, kt + 1);    // async fill of other buffer under compute
    const char* Ab = (const char*)(As + buf * 4096);
    const char* Bb = (const char*)(Bs + buf * 8192);
    #pragma unroll
    for (int ks = 0; ks < 2; ++ks) {
      bf16x8 af[2], bb[4];
      #pragma unroll
      for (int mi = 0; mi < 2; mi++) {
        int rr = wm * 32 + mi * 16 + l16;
        int cc = ks * 4 + lhi;
        af[mi] = *(const bf16x8*)(Ab + rr * 128 + ((cc ^ (rr & 7)) * 16));
      }
      #pragma unroll
      for (int ni = 0; ni < 4; ni++) {
        int rr = wn * 64 + ni * 16 + l16;
        int cc = ks * 4 + lhi;
        bb[ni] = *(const bf16x8*)(Bb + rr * 128 + ((cc ^ (rr & 7)) * 16));
      }
      #pragma unroll
      for (int mi = 0; mi < 2; mi++)
        #pragma unroll
        for (int ni = 0; ni < 4; ni++)
          acc[mi][ni] = MFMA16(af[mi], bb[ni], acc[mi][ni]);
    }
    __syncthreads();                       // drains staged loads; buf^1 ready next iter
  }

  if constexpr (MODE == 2) {
    const int r0 = rowBase + wm * 32 + lhi * 4;
    const int c0 = colBase + wn * 64 + l16;
    #pragma unroll
    for (int mi = 0; mi < 2; mi++)
      #pragma unroll
      for (int ni = 0; ni < 4; ni++)
        #pragma unroll
        for (int r = 0; r < 4; r++)
          ((float*)out0)[(size_t)(r0 + mi * 16 + r) * 512 + c0 + ni * 16] = acc[mi][ni][r];
  } else {
    // stage 64x128 packed tile (4 regions x 2048 shorts = 16 KB) in LDS, then coalesced write
    unsigned short* stg = smem;
    const bool isV = (MODE == 1) && (colBase >= 512);
    if (!isV) {
      #pragma unroll
      for (int mi = 0; mi < 2; mi++) {
        int rl = wm * 32 + mi * 16 + lhi * 4;
        int tl = rl >> 5;
        #pragma unroll
        for (int ni = 0; ni < 4; ni++) {
          int cl = wn * 64 + ni * 16 + l16;
          int hl = cl >> 6, d = cl & 63;
          int rbase = (hl * 2 + tl) * 2048 + (d >> 4) * 512 + 256 * ((d >> 3) & 1) + (d & 7);
          #pragma unroll
          for (int r = 0; r < 4; r++)
            stg[rbase + ((rl + r) & 31) * 8] = f2bf(acc[mi][ni][r]);
        }
      }
    } else {
      #pragma unroll
      for (int mi = 0; mi < 2; mi++) {
        int rl = wm * 32 + mi * 16 + lhi * 4;
        int tl = rl >> 5, kvr = rl & 31;
        #pragma unroll
        for (int ni = 0; ni < 4; ni++) {
          int cl = wn * 64 + ni * 16 + l16;
          int hl = cl >> 6, d = cl & 63;
          int off = (hl * 2 + tl) * 2048 + (d >> 5) * 1024 + ((kvr >> 4) & 1) * 512
                  + ((d & 31) + 32 * ((kvr >> 3) & 1)) * 8 + (kvr & 7);
          ushort4 p = make_ushort4(f2bf(acc[mi][ni][0]), f2bf(acc[mi][ni][1]),
                                   f2bf(acc[mi][ni][2]), f2bf(acc[mi][ni][3]));
          *(ushort4*)(stg + off) = p;
        }
      }
    }
    __syncthreads();
    const int bb2 = rowBase >> 11;
    const int hh0 = (colBase & 511) >> 6;
    const int tile0 = (rowBase & 2047) >> 5;
    unsigned short* gout = (unsigned short*)(isV ? out1 : out0);
    #pragma unroll
    for (int ridx = 0; ridx < 4; ridx++) {
      int hl = ridx >> 1, tl = ridx & 1;
      size_t gb = ((size_t)((bb2 * 8 + hh0 + hl) * 64 + tile0 + tl)) * 2048 + t * 8;
      *(uint4*)(gout + gb) = *(const uint4*)(stg + ridx * 2048 + t * 8);
    }
  }
}

// 768 blocks: xcd = bid&7 owns M-stripe of 512 rows (8 mtiles x 12 coltiles).
__global__ __launch_bounds__(256, 2) void k_qkv(
    const unsigned short* __restrict__ xn, const unsigned short* __restrict__ WqT,
    unsigned short* __restrict__ Qp,
    const unsigned short* __restrict__ cb, const unsigned short* __restrict__ WkvT,
    unsigned short* __restrict__ Kp, unsigned short* __restrict__ Vp)
{
  __shared__ __align__(16) unsigned short smem[2*64*64 + 2*128*64];
  const int bid = blockIdx.x;
  const int xcd = bid & 7, loc = bid >> 3;
  const int mloc = loc / 12, ct = loc % 12;
  const int mtile = xcd * 8 + mloc;
  if (ct < 4) gemm_body<0>(xn, WqT, Qp, nullptr, ct, mtile, smem);
  else        gemm_body<1>(cb, WkvT, Kp, Vp, ct - 4, mtile, smem);
}

// 256 blocks: xcd stripe, 8 mtiles x 4 coltiles per xcd.
__global__ __launch_bounds__(256, 2) void k_oproj(
    const unsigned short* __restrict__ ao, const unsigned short* __restrict__ WoT,
    float* __restrict__ proj)
{
  __shared__ __align__(16) unsigned short smem[2*64*64 + 2*128*64];
  const int bid = blockIdx.x;
  const int xcd = bid & 7, loc = bid >> 3;
  const int mloc = loc >> 2, ct = loc & 3;
  const int mtile = xcd * 8 + mloc;
  gemm_body<2>(ao, WoT, proj, nullptr, ct, mtile, smem);
}

// ---------------- flash attention v6 ----------------
// 256 blocks, 4 waves; each wave owns ONE q-tile (4 tiles/block), all waves share
// the SAME kv stream staged into LDS double-buffers via global_load_lds (async DMA).
// Barrier per kv-tile keeps waves in lockstep; DMA of tile it+1 hides under compute
// of tile it (GEMM-proven pattern). Block KV traffic: 512 KB for 4 q-tiles (4x reuse).
__global__ __launch_bounds__(256, 1) void k_attn(
    const unsigned short* __restrict__ Qp, const unsigned short* __restrict__ Kp,
    const unsigned short* __restrict__ Vp, const unsigned int* __restrict__ mb,
    unsigned short* __restrict__ O)
{
  __shared__ __align__(16) unsigned short Kb[2][2048];        // 2 x 4 KB
  __shared__ __align__(16) unsigned short Vb[2][2048];        // 2 x 4 KB
  __shared__ __align__(16) unsigned short otbuf[4][32 * 72];  // per-wave transpose buffer
  const int t = threadIdx.x, lane = t & 63, q5 = lane & 31, hi = lane >> 5;
  const int w = t >> 6;
  const int bid = blockIdx.x;
  const int bh = (bid & 7) * 2 + ((bid >> 7) & 1);   // XCD-local bh
  const int qt = ((bid >> 3) & 15) * 4 + w;          // per-wave q-tile
  const int q0 = qt * 32;
  const int b = bh >> 3, h = bh & 7;
  const float C2f = 0.022542110013890053f;           // SCALE^2 * log2(e)

  bf16x8 qf[4];
  {
    const unsigned short* qp = Qp + (size_t)(bh * 64 + qt) * 2048 + lane * 8;
    #pragma unroll
    for (int kk = 0; kk < 4; kk++) qf[kk] = *(const bf16x8*)(qp + kk * 512);
  }
  const unsigned short* kpb = Kp + (size_t)bh * 131072;
  const unsigned short* vpb = Vp + (size_t)bh * 131072;
  const unsigned int* mbp = mb + b * 64;

  float mrun = -3e38f, lrun = 0.f;
  f32x16 acc0, acc1;
  #pragma unroll
  for (int i = 0; i < 16; i++) { acc0[i] = 0.f; acc1[i] = 0.f; }

  // stage one 32-kv tile (K 4KB + V 4KB): 256 threads x 16B each, contiguous
  auto STAGE = [&](int buf, int tile) {
    stage16(kpb + (size_t)tile * 2048 + t * 8, Kb[buf] + t * 8);
    stage16(vpb + (size_t)tile * 2048 + t * 8, Vb[buf] + t * 8);
  };

  STAGE(0, 0);
  __syncthreads();                                   // vmcnt drain + barrier: buf0 ready
  for (int it = 0; it < 64; ++it) {
    const int buf = it & 1;
    if (it < 63) STAGE(buf ^ 1, it + 1);             // async fill under compute

    bf16x8 kf[4], vf[4];
    #pragma unroll
    for (int kk = 0; kk < 4; kk++) kf[kk] = *(const bf16x8*)(Kb[buf] + kk * 512 + lane * 8);
    #pragma unroll
    for (int i = 0; i < 4; i++)   vf[i]  = *(const bf16x8*)(Vb[buf] + i * 512 + lane * 8);

    // ---- QK^T ----
    f32x16 s;
    #pragma unroll
    for (int i = 0; i < 16; i++) s[i] = 0.f;
    #pragma unroll
    for (int kk = 0; kk < 4; kk++) s = MFMA32(kf[kk], qf[kk], s);

    // ---- online softmax ----
    float m0 = fmaxf(fmaxf(s[0], s[1]),  fmaxf(s[2], s[3]));
    float m1 = fmaxf(fmaxf(s[4], s[5]),  fmaxf(s[6], s[7]));
    float m2 = fmaxf(fmaxf(s[8], s[9]),  fmaxf(s[10], s[11]));
    float m3 = fmaxf(fmaxf(s[12], s[13]), fmaxf(s[14], s[15]));
    float tmax = fmaxf(fmaxf(m0, m1), fmaxf(m2, m3));
    tmax = fmaxf(tmax, __shfl_xor(tmax, 32));
    if (!__all(tmax <= mrun + 400.f)) {              // defer-max: rare
      float mnew = fmaxf(mrun, tmax);
      float sf = fexp2((mrun - mnew) * C2f);
      lrun *= sf;
      #pragma unroll
      for (int i = 0; i < 16; i++) { acc0[i] *= sf; acc1[i] *= sf; }
      mrun = mnew;
    }
    unsigned mh = mbp[it] >> (hi * 4);
    float nb = -mrun * C2f;
    float p[16];
    #pragma unroll
    for (int r = 0; r < 16; r++) {
      float pv = fexp2(fmaf(s[r], C2f, nb));
      p[r] = ((mh >> ((r & 3) + 8 * (r >> 2))) & 1u) ? pv : 0.f;
    }
    float rsa = (p[0] + p[1]) + (p[2] + p[3]);
    float rsb = (p[4] + p[5]) + (p[6] + p[7]);
    float rsc = (p[8] + p[9]) + (p[10] + p[11]);
    float rsd = (p[12] + p[13]) + (p[14] + p[15]);
    float rs = (rsa + rsb) + (rsc + rsd);
    rs += __shfl_xor(rs, 32);
    lrun += rs;

    unsigned wd[8];
    #pragma unroll
    for (int i = 0; i < 8; i++) wd[i] = cvtpk(p[2 * i], p[2 * i + 1]);
    plswap(wd[0], wd[2]); plswap(wd[1], wd[3]);
    plswap(wd[4], wd[6]); plswap(wd[5], wd[7]);
    union { unsigned u[4]; bf16x8 v; } U0, U1;
    U0.u[0] = wd[0]; U0.u[1] = wd[1]; U0.u[2] = wd[2]; U0.u[3] = wd[3];
    U1.u[0] = wd[4]; U1.u[1] = wd[5]; U1.u[2] = wd[6]; U1.u[3] = wd[7];

    // ---- PV ----
    acc0 = MFMA32(vf[0], U0.v, acc0);
    acc0 = MFMA32(vf[1], U1.v, acc0);
    acc1 = MFMA32(vf[2], U0.v, acc1);
    acc1 = MFMA32(vf[3], U1.v, acc1);

    __syncthreads();                                 // staged buf^1 complete; buf free
  }

  // ---- per-wave epilogue: normalize, transpose O^T[d][q] -> O[q][d] via LDS ----
  {
    float linv = 1.f / lrun;
    unsigned short* ot = otbuf[w];
    #pragma unroll
    for (int d2 = 0; d2 < 2; d2++)
      #pragma unroll
      for (int i = 0; i < 8; i++) {
        int d0 = ((2 * i) & 3) + 8 * (i >> 1) + 4 * hi + 32 * d2;
        float lo = (d2 ? acc1[2 * i]     : acc0[2 * i])     * linv;
        float hv = (d2 ? acc1[2 * i + 1] : acc0[2 * i + 1]) * linv;
        *(unsigned*)(ot + q5 * 72 + d0) = cvtpk(lo, hv);
      }
    // wave-private LDS, in-order within a wave: no barrier needed
    #pragma unroll
    for (int it2 = 0; it2 < 4; ++it2) {
      int row = (lane >> 3) + it2 * 8, ch = lane & 7;
      uint4 val = *(const uint4*)(ot + row * 72 + ch * 8);
      *(uint4*)(O + ((size_t)(b * 2048 + q0 + row)) * 512 + h * 64 + ch * 8) = val;
    }
  }
}

// ---------------- host ----------------
extern "C" void kernel_launch(void* const* d_in, const int* in_sizes, int n_in,
                              void* d_out, int out_size, void* d_ws, size_t ws_size,
                              hipStream_t stream) {
  const float* x     = (const float*)d_in[0];
  const float* ctx   = (const float*)d_in[1];
  const int*   mask  = (const int*)d_in[2];
  const float* ln_g  = (const float*)d_in[3];
  const float* ln_b  = (const float*)d_in[4];
  const float* Wq    = (const float*)d_in[5];
  const float* Wkv   = (const float*)d_in[6];
  const float* Wo    = (const float*)d_in[7];
  const float* lno_g = (const float*)d_in[8];
  const float* lno_b = (const float*)d_in[9];
  float* out = (float*)d_out;

  char* ws = (char*)d_ws;
  unsigned short* WqT  = (unsigned short*)(ws + 0);                         // 512 KB
  unsigned short* WkvT = (unsigned short*)(ws + (size_t)1 * (1 << 19));     // 1 MB
  unsigned short* WoT  = (unsigned short*)(ws + (size_t)3 * (1 << 19));     // 512 KB
  unsigned short* xn   = (unsigned short*)(ws + (size_t)2  * (1 << 20));    // 4 MB
  unsigned short* cb   = (unsigned short*)(ws + (size_t)6  * (1 << 20));    // 4 MB
  unsigned short* Qp   = (unsigned short*)(ws + (size_t)10 * (1 << 20));    // 4 MB (fragment-packed)
  unsigned short* Kp   = (unsigned short*)(ws + (size_t)14 * (1 << 20));    // 4 MB (fragment-packed)
  unsigned short* Vp   = (unsigned short*)(ws + (size_t)18 * (1 << 20));    // 4 MB (fragment-packed)
  unsigned short* ao   = (unsigned short*)(ws + (size_t)22 * (1 << 20));    // 4 MB
  float* proj          = (float*)(ws + (size_t)26 * (1 << 20));             // 8 MB
  unsigned int* mbw    = (unsigned int*)(ws + (size_t)26 * (1 << 20));      // 512 B, overlaps proj (dead by then)

  k_prep<<<4112, 256, 0, stream>>>(Wq, Wkv, Wo, x, ln_g, ln_b, ctx, mask,
                                   WqT, WkvT, WoT, xn, cb, mbw);
  k_qkv<<<768, 256, 0, stream>>>(xn, WqT, Qp, cb, WkvT, Kp, Vp);
  k_attn<<<256, 256, 0, stream>>>(Qp, Kp, Vp, mbw, ao);
  k_oproj<<<256, 256, 0, stream>>>(ao, WoT, proj);
  k_layernorm_f<<<1024, 256, 0, stream>>>(proj, lno_g, lno_b, out);
}

// Round 10
// 63.226 us; speedup vs baseline: 1.4494x; 1.4494x over previous
//
#include <hip/hip_runtime.h>
#include <stdint.h>

typedef float f32x4 __attribute__((ext_vector_type(4)));
typedef float f32x16 __attribute__((ext_vector_type(16)));
typedef __bf16 bf16x8 __attribute__((ext_vector_type(8)));
typedef unsigned int uint2v __attribute__((ext_vector_type(2)));

#define MFMA16(a,b,c) __builtin_amdgcn_mfma_f32_16x16x32_bf16((a),(b),(c),0,0,0)
#define MFMA32(a,b,c) __builtin_amdgcn_mfma_f32_32x32x16_bf16((a),(b),(c),0,0,0)

__device__ __forceinline__ unsigned short f2bf(float f){
  unsigned int u = __float_as_uint(f);
  u += 0x7FFFu + ((u >> 16) & 1u);
  return (unsigned short)(u >> 16);
}

__device__ __forceinline__ unsigned cvtpk(float lo, float hi){
  unsigned r;
  asm volatile("v_cvt_pk_bf16_f32 %0, %1, %2" : "=v"(r) : "v"(lo), "v"(hi));
  return r;
}

__device__ __forceinline__ float fexp2(float x){
#if __has_builtin(__builtin_amdgcn_exp2f)
  return __builtin_amdgcn_exp2f(x);
#else
  return exp2f(x);
#endif
}

__device__ __forceinline__ void plswap(unsigned &a, unsigned &b){
#if __has_builtin(__builtin_amdgcn_permlane32_swap)
  uint2v r = __builtin_amdgcn_permlane32_swap(a, b, false, false);
  a = r[0]; b = r[1];
#else
  unsigned xa = __shfl_xor(a, 32), xb = __shfl_xor(b, 32);
  int hi = (threadIdx.x & 63) >> 5;
  unsigned na = hi ? xb : a;
  unsigned nb = hi ? b : xa;
  a = na; b = nb;
#endif
}

// pairwise (lane, lane^32) max / sum via permlane32_swap — pure VALU, no LDS
__device__ __forceinline__ float xpair_max(float x){
  unsigned a = __float_as_uint(x), b = a;
  plswap(a, b);
  return fmaxf(__uint_as_float(a), __uint_as_float(b));
}
__device__ __forceinline__ float xpair_sum(float x){
  unsigned a = __float_as_uint(x), b = a;
  plswap(a, b);
  return __uint_as_float(a) + __uint_as_float(b);
}

// async global -> LDS, 16B per lane; LDS dest is wave-uniform base + lane*16
__device__ __forceinline__ void stage16(const unsigned short* g, unsigned short* l){
  __builtin_amdgcn_global_load_lds(
      (const __attribute__((address_space(1))) void*)g,
      (__attribute__((address_space(3))) void*)l, 16, 0, 0);
}

// ---------------- prep router: weight transposes + LN(x) + cast(ctx) + maskbits ----------------
__global__ __launch_bounds__(256) void k_prep(
    const float* __restrict__ Wq, const float* __restrict__ Wkv, const float* __restrict__ Wo,
    const float* __restrict__ x, const float* __restrict__ ln_g, const float* __restrict__ ln_b,
    const float* __restrict__ ctx, const int* __restrict__ mask,
    unsigned short* __restrict__ WqT, unsigned short* __restrict__ WkvT, unsigned short* __restrict__ WoT,
    unsigned short* __restrict__ xn, unsigned short* __restrict__ cb, unsigned int* __restrict__ mb)
{
  __shared__ float tile[32][33];
  const int bid = blockIdx.x, t = threadIdx.x;
  if (bid < 1024) {
    const float* W; unsigned short* WT; int N, bx, by;
    if (bid < 256)      { W = Wq;  WT = WqT;  N = 512;  bx = bid & 15;        by = bid >> 4; }
    else if (bid < 768) { W = Wkv; WT = WkvT; N = 1024; bx = (bid-256) & 31;  by = (bid-256) >> 5; }
    else                { W = Wo;  WT = WoT;  N = 512;  bx = (bid-768) & 15;  by = (bid-768) >> 4; }
    const int tx = t & 31, ty = t >> 5;
    #pragma unroll
    for (int i = 0; i < 4; i++)
      tile[ty + i*8][tx] = W[(size_t)(by*32 + ty + i*8) * N + bx*32 + tx];
    __syncthreads();
    #pragma unroll
    for (int i = 0; i < 4; i++)
      WT[(size_t)(bx*32 + ty + i*8) * 512 + by*32 + tx] = f2bf(tile[tx][ty + i*8]);
  } else if (bid < 2048) {
    int row = (bid - 1024) * 4 + (t >> 6);
    int lane = t & 63;
    const float4* xr = (const float4*)(x + (size_t)row * 512);
    float4 a = xr[lane], c = xr[64 + lane];
    float s = a.x + a.y + a.z + a.w + c.x + c.y + c.z + c.w;
    #pragma unroll
    for (int o = 32; o; o >>= 1) s += __shfl_xor(s, o);
    float mu = s * (1.0f / 512.0f);
    float va = (a.x-mu)*(a.x-mu) + (a.y-mu)*(a.y-mu) + (a.z-mu)*(a.z-mu) + (a.w-mu)*(a.w-mu)
             + (c.x-mu)*(c.x-mu) + (c.y-mu)*(c.y-mu) + (c.z-mu)*(c.z-mu) + (c.w-mu)*(c.w-mu);
    #pragma unroll
    for (int o = 32; o; o >>= 1) va += __shfl_xor(va, o);
    float inv = rsqrtf(va * (1.0f / 512.0f) + 1e-5f);
    const float4* gp = (const float4*)ln_g;
    const float4* bp = (const float4*)ln_b;
    float4 g0 = gp[lane], g1 = gp[64 + lane], b0 = bp[lane], b1 = bp[64 + lane];
    ushort4* op = (ushort4*)(xn + (size_t)row * 512);
    op[lane]      = make_ushort4(f2bf((a.x-mu)*inv*g0.x + b0.x), f2bf((a.y-mu)*inv*g0.y + b0.y),
                                 f2bf((a.z-mu)*inv*g0.z + b0.z), f2bf((a.w-mu)*inv*g0.w + b0.w));
    op[64 + lane] = make_ushort4(f2bf((c.x-mu)*inv*g1.x + b1.x), f2bf((c.y-mu)*inv*g1.y + b1.y),
                                 f2bf((c.z-mu)*inv*g1.z + b1.z), f2bf((c.w-mu)*inv*g1.w + b1.w));
  } else if (bid < 4096) {
    int i = (bid - 2048) * 256 + t;
    float4 v = ((const float4*)ctx)[i];
    ((ushort4*)cb)[i] = make_ushort4(f2bf(v.x), f2bf(v.y), f2bf(v.z), f2bf(v.w));
  } else {
    int g = (bid - 4096) * 4 + (t >> 6);
    int ln = t & 63;
    int v = mask[g * 64 + ln];
    unsigned long long bb = __ballot(v != 0);
    if (ln == 0) { mb[g*2] = (unsigned)bb; mb[g*2+1] = (unsigned)(bb >> 32); }
  }
}

// ---------------- final layernorm (f32 in/out) ----------------
__global__ __launch_bounds__(256) void k_layernorm_f(
    const float* __restrict__ X, const float* __restrict__ G,
    const float* __restrict__ Bt, float* __restrict__ out)
{
  int row = blockIdx.x * 4 + (threadIdx.x >> 6);
  int lane = threadIdx.x & 63;
  const float4* xr = (const float4*)(X + (size_t)row * 512);
  float4 a = xr[lane], c = xr[64 + lane];
  float s = a.x + a.y + a.z + a.w + c.x + c.y + c.z + c.w;
  #pragma unroll
  for (int o = 32; o; o >>= 1) s += __shfl_xor(s, o);
  float mu = s * (1.0f / 512.0f);
  float va = (a.x-mu)*(a.x-mu) + (a.y-mu)*(a.y-mu) + (a.z-mu)*(a.z-mu) + (a.w-mu)*(a.w-mu)
           + (c.x-mu)*(c.x-mu) + (c.y-mu)*(c.y-mu) + (c.z-mu)*(c.z-mu) + (c.w-mu)*(c.w-mu);
  #pragma unroll
  for (int o = 32; o; o >>= 1) va += __shfl_xor(va, o);
  float inv = rsqrtf(va * (1.0f / 512.0f) + 1e-5f);
  const float4* gp = (const float4*)G;
  const float4* bp = (const float4*)Bt;
  float4 g0 = gp[lane], g1 = gp[64 + lane], b0 = bp[lane], b1 = bp[64 + lane];
  float4 y0, y1;
  y0.x = (a.x-mu)*inv*g0.x + b0.x; y0.y = (a.y-mu)*inv*g0.y + b0.y;
  y0.z = (a.z-mu)*inv*g0.z + b0.z; y0.w = (a.w-mu)*inv*g0.w + b0.w;
  y1.x = (c.x-mu)*inv*g1.x + b1.x; y1.y = (c.y-mu)*inv*g1.y + b1.y;
  y1.z = (c.z-mu)*inv*g1.z + b1.z; y1.w = (c.w-mu)*inv*g1.w + b1.w;
  float4* op = (float4*)(out + (size_t)row * 512);
  op[lane] = y0; op[64 + lane] = y1;
}

// ---------------- bf16 MFMA GEMM body: 64x128 tile, BK=64, 4 waves (2x2) ----------------
// Staging via global_load_lds (async DMA, no staging VGPRs), double-buffered LDS,
// one __syncthreads per K-step. Swizzle applied on the GLOBAL source address;
// LDS dest linear per wave (wave-uniform base + lane*16B).
// MODE 0: fragment-packed Q out. MODE 1: KV -> packed Kp (col<512) / Vp. MODE 2: f32 out.
template<int MODE>
__device__ __forceinline__ void gemm_body(
    const unsigned short* __restrict__ A, const unsigned short* __restrict__ BT,
    void* __restrict__ out0, void* __restrict__ out1, int bx, int by,
    unsigned short* smem)
{
  unsigned short* As = smem;              // [2][64*64]  = 16 KB
  unsigned short* Bs = smem + 2*64*64;    // [2][128*64] = 32 KB
  const int t = threadIdx.x;
  const int lane = t & 63, l16 = lane & 15, lhi = lane >> 4;
  const int w = t >> 6, wm = w >> 1, wn = w & 1;
  const int rowBase = by * 64;
  const int colBase = bx * 128;
  const int srr = lane >> 3, scw = lane & 7;

  f32x4 acc[2][4];
  #pragma unroll
  for (int i = 0; i < 2; i++)
    #pragma unroll
    for (int j = 0; j < 4; j++)
      acc[i][j] = f32x4{0.f, 0.f, 0.f, 0.f};

  auto STAGE = [&](int buf, int kt) {
    unsigned short* Ab = As + buf * 4096;
    unsigned short* Bb = Bs + buf * 8192;
    #pragma unroll
    for (int i = 0; i < 2; i++) {
      int rr = i * 32 + w * 8 + srr;
      stage16(A + (size_t)(rowBase + rr) * 512 + kt * 64 + ((scw ^ (rr & 7)) * 8),
              Ab + (i * 32 + w * 8) * 64);
    }
    #pragma unroll
    for (int i = 0; i < 4; i++) {
      int rr = i * 32 + w * 8 + srr;
      stage16(BT + (size_t)(colBase + rr) * 512 + kt * 64 + ((scw ^ (rr & 7)) * 8),
              Bb + (i * 32 + w * 8) * 64);
    }
  };

  STAGE(0, 0);
  __syncthreads();                         // vmcnt(0) drain + barrier: buf0 ready
  for (int kt = 0; kt < 8; ++kt) {
    const int buf = kt & 1;
    if (kt < 7) STAGE(buf ^ 1, kt + 1);    // async fill of other buffer under compute
    const char* Ab = (const char*)(As + buf * 4096);
    const char* Bb = (const char*)(Bs + buf * 8192);
    #pragma unroll
    for (int ks = 0; ks < 2; ++ks) {
      bf16x8 af[2], bb[4];
      #pragma unroll
      for (int mi = 0; mi < 2; mi++) {
        int rr = wm * 32 + mi * 16 + l16;
        int cc = ks * 4 + lhi;
        af[mi] = *(const bf16x8*)(Ab + rr * 128 + ((cc ^ (rr & 7)) * 16));
      }
      #pragma unroll
      for (int ni = 0; ni < 4; ni++) {
        int rr = wn * 64 + ni * 16 + l16;
        int cc = ks * 4 + lhi;
        bb[ni] = *(const bf16x8*)(Bb + rr * 128 + ((cc ^ (rr & 7)) * 16));
      }
      #pragma unroll
      for (int mi = 0; mi < 2; mi++)
        #pragma unroll
        for (int ni = 0; ni < 4; ni++)
          acc[mi][ni] = MFMA16(af[mi], bb[ni], acc[mi][ni]);
    }
    __syncthreads();                       // drains staged loads; buf^1 ready next iter
  }

  if constexpr (MODE == 2) {
    const int r0 = rowBase + wm * 32 + lhi * 4;
    const int c0 = colBase + wn * 64 + l16;
    #pragma unroll
    for (int mi = 0; mi < 2; mi++)
      #pragma unroll
      for (int ni = 0; ni < 4; ni++)
        #pragma unroll
        for (int r = 0; r < 4; r++)
          ((float*)out0)[(size_t)(r0 + mi * 16 + r) * 512 + c0 + ni * 16] = acc[mi][ni][r];
  } else {
    // stage 64x128 packed tile (4 regions x 2048 shorts = 16 KB) in LDS, then coalesced write
    unsigned short* stg = smem;
    const bool isV = (MODE == 1) && (colBase >= 512);
    if (!isV) {
      #pragma unroll
      for (int mi = 0; mi < 2; mi++) {
        int rl = wm * 32 + mi * 16 + lhi * 4;
        int tl = rl >> 5;
        #pragma unroll
        for (int ni = 0; ni < 4; ni++) {
          int cl = wn * 64 + ni * 16 + l16;
          int hl = cl >> 6, d = cl & 63;
          int rbase = (hl * 2 + tl) * 2048 + (d >> 4) * 512 + 256 * ((d >> 3) & 1) + (d & 7);
          #pragma unroll
          for (int r = 0; r < 4; r++)
            stg[rbase + ((rl + r) & 31) * 8] = f2bf(acc[mi][ni][r]);
        }
      }
    } else {
      #pragma unroll
      for (int mi = 0; mi < 2; mi++) {
        int rl = wm * 32 + mi * 16 + lhi * 4;
        int tl = rl >> 5, kvr = rl & 31;
        #pragma unroll
        for (int ni = 0; ni < 4; ni++) {
          int cl = wn * 64 + ni * 16 + l16;
          int hl = cl >> 6, d = cl & 63;
          int off = (hl * 2 + tl) * 2048 + (d >> 5) * 1024 + ((kvr >> 4) & 1) * 512
                  + ((d & 31) + 32 * ((kvr >> 3) & 1)) * 8 + (kvr & 7);
          ushort4 p = make_ushort4(f2bf(acc[mi][ni][0]), f2bf(acc[mi][ni][1]),
                                   f2bf(acc[mi][ni][2]), f2bf(acc[mi][ni][3]));
          *(ushort4*)(stg + off) = p;
        }
      }
    }
    __syncthreads();
    const int bb2 = rowBase >> 11;
    const int hh0 = (colBase & 511) >> 6;
    const int tile0 = (rowBase & 2047) >> 5;
    unsigned short* gout = (unsigned short*)(isV ? out1 : out0);
    #pragma unroll
    for (int ridx = 0; ridx < 4; ridx++) {
      int hl = ridx >> 1, tl = ridx & 1;
      size_t gb = ((size_t)((bb2 * 8 + hh0 + hl) * 64 + tile0 + tl)) * 2048 + t * 8;
      *(uint4*)(gout + gb) = *(const uint4*)(stg + ridx * 2048 + t * 8);
    }
  }
}

// 768 blocks: xcd = bid&7 owns M-stripe of 512 rows (8 mtiles x 12 coltiles).
__global__ __launch_bounds__(256, 2) void k_qkv(
    const unsigned short* __restrict__ xn, const unsigned short* __restrict__ WqT,
    unsigned short* __restrict__ Qp,
    const unsigned short* __restrict__ cb, const unsigned short* __restrict__ WkvT,
    unsigned short* __restrict__ Kp, unsigned short* __restrict__ Vp)
{
  __shared__ __align__(16) unsigned short smem[2*64*64 + 2*128*64];
  const int bid = blockIdx.x;
  const int xcd = bid & 7, loc = bid >> 3;
  const int mloc = loc / 12, ct = loc % 12;
  const int mtile = xcd * 8 + mloc;
  if (ct < 4) gemm_body<0>(xn, WqT, Qp, nullptr, ct, mtile, smem);
  else        gemm_body<1>(cb, WkvT, Kp, Vp, ct - 4, mtile, smem);
}

// 256 blocks: xcd stripe, 8 mtiles x 4 coltiles per xcd.
__global__ __launch_bounds__(256, 2) void k_oproj(
    const unsigned short* __restrict__ ao, const unsigned short* __restrict__ WoT,
    float* __restrict__ proj)
{
  __shared__ __align__(16) unsigned short smem[2*64*64 + 2*128*64];
  const int bid = blockIdx.x;
  const int xcd = bid & 7, loc = bid >> 3;
  const int mloc = loc >> 2, ct = loc & 3;
  const int mtile = xcd * 8 + mloc;
  gemm_body<2>(ao, WoT, proj, nullptr, ct, mtile, smem);
}

// ---------------- flash attention v7 (v4 + permlane reductions + setprio) ----------------
// 1024 blocks, 4 waves; XCD-swizzled decode. Wave w owns kv quarter [w*512, +512).
// Q/K/V fragment-packed (coalesced 16B/lane). Register prefetch 1 tile deep.
// Cross-32 max via permlane32_swap (VALU, no LDS); l-sum cross-32 deferred to merge.
__global__ __launch_bounds__(256, 3) void k_attn(
    const unsigned short* __restrict__ Qp, const unsigned short* __restrict__ Kp,
    const unsigned short* __restrict__ Vp, const unsigned int* __restrict__ mb,
    unsigned short* __restrict__ O)
{
  __shared__ __align__(16) float mbuf[3][64][34];   // acc(32) + m + l per lane
  const int t = threadIdx.x, lane = t & 63, q5 = lane & 31, hi = lane >> 5;
  const int w = t >> 6;
  const int bid = blockIdx.x;
  const int bh = (bid & 7) * 2 + (bid >> 9);        // XCD-local bh pair
  const int qt = (bid >> 3) & 63;
  const int q0 = qt * 32;
  const int b = bh >> 3, h = bh & 7;
  const float C2f = 0.022542110013890053f;          // SCALE^2 * log2(e)

  bf16x8 qf[4];
  {
    const unsigned short* qp = Qp + (size_t)(bh * 64 + qt) * 2048 + lane * 8;
    #pragma unroll
    for (int kk = 0; kk < 4; kk++) qf[kk] = *(const bf16x8*)(qp + kk * 512);
  }
  const unsigned short* kpb = Kp + (size_t)bh * 131072 + lane * 8;
  const unsigned short* vpb = Vp + (size_t)bh * 131072 + lane * 8;
  const unsigned int* mbp = mb + b * 64;

  float mrun = -3e38f, lrun = 0.f;                  // lrun is a PER-LANE partial
  f32x16 acc0, acc1;
  #pragma unroll
  for (int i = 0; i < 16; i++) { acc0[i] = 0.f; acc1[i] = 0.f; }

  bf16x8 kf[4], vf[4];
  auto loadK = [&](int tile) {
    #pragma unroll
    for (int kk = 0; kk < 4; kk++)
      kf[kk] = *(const bf16x8*)(kpb + (size_t)tile * 2048 + kk * 512);
  };
  auto loadV = [&](int tile) {
    #pragma unroll
    for (int i = 0; i < 4; i++)
      vf[i] = *(const bf16x8*)(vpb + (size_t)tile * 2048 + i * 512);
  };

  const int tb = w * 16;
  loadK(tb); loadV(tb);
  for (int it = 0; it < 16; ++it) {
    const int ti = tb + it;

    // ---- QK^T ----
    f32x16 s;
    #pragma unroll
    for (int i = 0; i < 16; i++) s[i] = 0.f;
    __builtin_amdgcn_s_setprio(1);
    #pragma unroll
    for (int kk = 0; kk < 4; kk++) s = MFMA32(kf[kk], qf[kk], s);
    __builtin_amdgcn_s_setprio(0);
    if (it < 15) loadK(ti + 1);      // kf dead: prefetch next K under softmax+PV

    // ---- online softmax ----
    float m0 = fmaxf(fmaxf(s[0], s[1]),  fmaxf(s[2], s[3]));
    float m1 = fmaxf(fmaxf(s[4], s[5]),  fmaxf(s[6], s[7]));
    float m2 = fmaxf(fmaxf(s[8], s[9]),  fmaxf(s[10], s[11]));
    float m3 = fmaxf(fmaxf(s[12], s[13]), fmaxf(s[14], s[15]));
    float tmax = fmaxf(fmaxf(m0, m1), fmaxf(m2, m3));
    tmax = xpair_max(tmax);                          // VALU cross-32 (no LDS)
    if (!__all(tmax <= mrun + 400.f)) {              // defer-max: rare
      float mnew = fmaxf(mrun, tmax);
      float sf = fexp2((mrun - mnew) * C2f);
      lrun *= sf;
      #pragma unroll
      for (int i = 0; i < 16; i++) { acc0[i] *= sf; acc1[i] *= sf; }
      mrun = mnew;
    }
    unsigned mh = mbp[ti] >> (hi * 4);
    float nb = -mrun * C2f;
    float p[16];
    #pragma unroll
    for (int r = 0; r < 16; r++) {
      float pv = fexp2(fmaf(s[r], C2f, nb));
      p[r] = ((mh >> ((r & 3) + 8 * (r >> 2))) & 1u) ? pv : 0.f;
    }
    float rsa = (p[0] + p[1]) + (p[2] + p[3]);
    float rsb = (p[4] + p[5]) + (p[6] + p[7]);
    float rsc = (p[8] + p[9]) + (p[10] + p[11]);
    float rsd = (p[12] + p[13]) + (p[14] + p[15]);
    lrun += (rsa + rsb) + (rsc + rsd);               // per-lane partial; cross-32 at merge

    unsigned wd[8];
    #pragma unroll
    for (int i = 0; i < 8; i++) wd[i] = cvtpk(p[2 * i], p[2 * i + 1]);
    plswap(wd[0], wd[2]); plswap(wd[1], wd[3]);
    plswap(wd[4], wd[6]); plswap(wd[5], wd[7]);
    union { unsigned u[4]; bf16x8 v; } U0, U1;
    U0.u[0] = wd[0]; U0.u[1] = wd[1]; U0.u[2] = wd[2]; U0.u[3] = wd[3];
    U1.u[0] = wd[4]; U1.u[1] = wd[5]; U1.u[2] = wd[6]; U1.u[3] = wd[7];

    // ---- PV ----
    __builtin_amdgcn_s_setprio(1);
    acc0 = MFMA32(vf[0], U0.v, acc0);
    acc0 = MFMA32(vf[1], U1.v, acc0);
    acc1 = MFMA32(vf[2], U0.v, acc1);
    acc1 = MFMA32(vf[3], U1.v, acc1);
    __builtin_amdgcn_s_setprio(0);
    if (it < 15) loadV(ti + 1);      // vf dead: prefetch next V under next QK+softmax
  }

  // ---- 4-way merge (lrun partials; final cross-32 sum once) ----
  if (w) {
    #pragma unroll
    for (int i = 0; i < 16; i++) { mbuf[w-1][lane][i] = acc0[i]; mbuf[w-1][lane][16 + i] = acc1[i]; }
    mbuf[w-1][lane][32] = mrun; mbuf[w-1][lane][33] = lrun;
  }
  __syncthreads();
  if (!w) {
    float mo[3], lo[3];
    #pragma unroll
    for (int wv = 0; wv < 3; wv++) { mo[wv] = mbuf[wv][lane][32]; lo[wv] = mbuf[wv][lane][33]; }
    float mN = fmaxf(fmaxf(mrun, mo[0]), fmaxf(mo[1], mo[2]));
    float sf0 = fexp2((mrun - mN) * C2f);
    float sfv[3];
    float lsum = lrun * sf0;
    #pragma unroll
    for (int wv = 0; wv < 3; wv++) { sfv[wv] = fexp2((mo[wv] - mN) * C2f); lsum += lo[wv] * sfv[wv]; }
    lsum = xpair_sum(lsum);                          // complete the row sum across lane pair
    float linv = 1.f / lsum;
    float a2[32];
    #pragma unroll
    for (int i = 0; i < 16; i++) {
      float v0 = acc0[i] * sf0, v1 = acc1[i] * sf0;
      #pragma unroll
      for (int wv = 0; wv < 3; wv++) {
        v0 += mbuf[wv][lane][i] * sfv[wv];
        v1 += mbuf[wv][lane][16 + i] * sfv[wv];
      }
      a2[i] = v0 * linv;
      a2[16 + i] = v1 * linv;
    }
    // transpose O^T[d][q] -> O[q][d] via LDS (stride 72 shorts, 16B-aligned rows)
    unsigned short* ot = (unsigned short*)&mbuf[0][0][0];
    #pragma unroll
    for (int d2 = 0; d2 < 2; d2++)
      #pragma unroll
      for (int i = 0; i < 8; i++) {
        int d0 = ((2 * i) & 3) + 8 * (i >> 1) + 4 * hi + 32 * d2;
        unsigned wv2 = cvtpk(a2[d2 * 16 + 2 * i], a2[d2 * 16 + 2 * i + 1]);
        *(unsigned*)(ot + q5 * 72 + d0) = wv2;
      }
    #pragma unroll
    for (int it2 = 0; it2 < 4; ++it2) {
      int row = (lane >> 3) + it2 * 8, ch = lane & 7;
      uint4 val = *(const uint4*)(ot + row * 72 + ch * 8);
      *(uint4*)(O + ((size_t)(b * 2048 + q0 + row)) * 512 + h * 64 + ch * 8) = val;
    }
  }
}

// ---------------- host ----------------
extern "C" void kernel_launch(void* const* d_in, const int* in_sizes, int n_in,
                              void* d_out, int out_size, void* d_ws, size_t ws_size,
                              hipStream_t stream) {
  const float* x     = (const float*)d_in[0];
  const float* ctx   = (const float*)d_in[1];
  const int*   mask  = (const int*)d_in[2];
  const float* ln_g  = (const float*)d_in[3];
  const float* ln_b  = (const float*)d_in[4];
  const float* Wq    = (const float*)d_in[5];
  const float* Wkv   = (const float*)d_in[6];
  const float* Wo    = (const float*)d_in[7];
  const float* lno_g = (const float*)d_in[8];
  const float* lno_b = (const float*)d_in[9];
  float* out = (float*)d_out;

  char* ws = (char*)d_ws;
  unsigned short* WqT  = (unsigned short*)(ws + 0);                         // 512 KB
  unsigned short* WkvT = (unsigned short*)(ws + (size_t)1 * (1 << 19));     // 1 MB
  unsigned short* WoT  = (unsigned short*)(ws + (size_t)3 * (1 << 19));     // 512 KB
  unsigned short* xn   = (unsigned short*)(ws + (size_t)2  * (1 << 20));    // 4 MB
  unsigned short* cb   = (unsigned short*)(ws + (size_t)6  * (1 << 20));    // 4 MB
  unsigned short* Qp   = (unsigned short*)(ws + (size_t)10 * (1 << 20));    // 4 MB (fragment-packed)
  unsigned short* Kp   = (unsigned short*)(ws + (size_t)14 * (1 << 20));    // 4 MB (fragment-packed)
  unsigned short* Vp   = (unsigned short*)(ws + (size_t)18 * (1 << 20));    // 4 MB (fragment-packed)
  unsigned short* ao   = (unsigned short*)(ws + (size_t)22 * (1 << 20));    // 4 MB
  float* proj          = (float*)(ws + (size_t)26 * (1 << 20));             // 8 MB
  unsigned int* mbw    = (unsigned int*)(ws + (size_t)26 * (1 << 20));      // 512 B, overlaps proj (dead by then)

  k_prep<<<4112, 256, 0, stream>>>(Wq, Wkv, Wo, x, ln_g, ln_b, ctx, mask,
                                   WqT, WkvT, WoT, xn, cb, mbw);
  k_qkv<<<768, 256, 0, stream>>>(xn, WqT, Qp, cb, WkvT, Kp, Vp);
  k_attn<<<1024, 256, 0, stream>>>(Qp, Kp, Vp, mbw, ao);
  k_oproj<<<256, 256, 0, stream>>>(ao, WoT, proj);
  k_layernorm_f<<<1024, 256, 0, stream>>>(proj, lno_g, lno_b, out);
}

// Round 11
// 61.678 us; speedup vs baseline: 1.4858x; 1.0251x over previous
//
#include <hip/hip_runtime.h>
#include <stdint.h>

typedef float f32x4 __attribute__((ext_vector_type(4)));
typedef float f32x16 __attribute__((ext_vector_type(16)));
typedef __bf16 bf16x8 __attribute__((ext_vector_type(8)));
typedef unsigned int uint2v __attribute__((ext_vector_type(2)));

#define MFMA16(a,b,c) __builtin_amdgcn_mfma_f32_16x16x32_bf16((a),(b),(c),0,0,0)
#define MFMA32(a,b,c) __builtin_amdgcn_mfma_f32_32x32x16_bf16((a),(b),(c),0,0,0)

__device__ __forceinline__ unsigned short f2bf(float f){
  unsigned int u = __float_as_uint(f);
  u += 0x7FFFu + ((u >> 16) & 1u);
  return (unsigned short)(u >> 16);
}

__device__ __forceinline__ unsigned cvtpk(float lo, float hi){
  unsigned r;
  asm volatile("v_cvt_pk_bf16_f32 %0, %1, %2" : "=v"(r) : "v"(lo), "v"(hi));
  return r;
}

__device__ __forceinline__ float fexp2(float x){
#if __has_builtin(__builtin_amdgcn_exp2f)
  return __builtin_amdgcn_exp2f(x);
#else
  return exp2f(x);
#endif
}

__device__ __forceinline__ void plswap(unsigned &a, unsigned &b){
#if __has_builtin(__builtin_amdgcn_permlane32_swap)
  uint2v r = __builtin_amdgcn_permlane32_swap(a, b, false, false);
  a = r[0]; b = r[1];
#else
  unsigned xa = __shfl_xor(a, 32), xb = __shfl_xor(b, 32);
  int hi = (threadIdx.x & 63) >> 5;
  unsigned na = hi ? xb : a;
  unsigned nb = hi ? b : xa;
  a = na; b = nb;
#endif
}

// pairwise (lane, lane^32) max / sum via permlane32_swap — pure VALU, no LDS
__device__ __forceinline__ float xpair_max(float x){
  unsigned a = __float_as_uint(x), b = a;
  plswap(a, b);
  return fmaxf(__uint_as_float(a), __uint_as_float(b));
}
__device__ __forceinline__ float xpair_sum(float x){
  unsigned a = __float_as_uint(x), b = a;
  plswap(a, b);
  return __uint_as_float(a) + __uint_as_float(b);
}

// async global -> LDS, 16B per lane; LDS dest is wave-uniform base + lane*16
__device__ __forceinline__ void stage16(const unsigned short* g, unsigned short* l){
  __builtin_amdgcn_global_load_lds(
      (const __attribute__((address_space(1))) void*)g,
      (__attribute__((address_space(3))) void*)l, 16, 0, 0);
}

// ---------------- prep router: weight transposes + LN(x) + cast(ctx) + maskbits ----------------
__global__ __launch_bounds__(256) void k_prep(
    const float* __restrict__ Wq, const float* __restrict__ Wkv, const float* __restrict__ Wo,
    const float* __restrict__ x, const float* __restrict__ ln_g, const float* __restrict__ ln_b,
    const float* __restrict__ ctx, const int* __restrict__ mask,
    unsigned short* __restrict__ WqT, unsigned short* __restrict__ WkvT, unsigned short* __restrict__ WoT,
    unsigned short* __restrict__ xn, unsigned short* __restrict__ cb, unsigned int* __restrict__ mb)
{
  __shared__ float tile[32][33];
  const int bid = blockIdx.x, t = threadIdx.x;
  if (bid < 1024) {
    const float* W; unsigned short* WT; int N, bx, by;
    if (bid < 256)      { W = Wq;  WT = WqT;  N = 512;  bx = bid & 15;        by = bid >> 4; }
    else if (bid < 768) { W = Wkv; WT = WkvT; N = 1024; bx = (bid-256) & 31;  by = (bid-256) >> 5; }
    else                { W = Wo;  WT = WoT;  N = 512;  bx = (bid-768) & 15;  by = (bid-768) >> 4; }
    const int tx = t & 31, ty = t >> 5;
    #pragma unroll
    for (int i = 0; i < 4; i++)
      tile[ty + i*8][tx] = W[(size_t)(by*32 + ty + i*8) * N + bx*32 + tx];
    __syncthreads();
    #pragma unroll
    for (int i = 0; i < 4; i++)
      WT[(size_t)(bx*32 + ty + i*8) * 512 + by*32 + tx] = f2bf(tile[tx][ty + i*8]);
  } else if (bid < 2048) {
    int row = (bid - 1024) * 4 + (t >> 6);
    int lane = t & 63;
    const float4* xr = (const float4*)(x + (size_t)row * 512);
    float4 a = xr[lane], c = xr[64 + lane];
    float s = a.x + a.y + a.z + a.w + c.x + c.y + c.z + c.w;
    #pragma unroll
    for (int o = 32; o; o >>= 1) s += __shfl_xor(s, o);
    float mu = s * (1.0f / 512.0f);
    float va = (a.x-mu)*(a.x-mu) + (a.y-mu)*(a.y-mu) + (a.z-mu)*(a.z-mu) + (a.w-mu)*(a.w-mu)
             + (c.x-mu)*(c.x-mu) + (c.y-mu)*(c.y-mu) + (c.z-mu)*(c.z-mu) + (c.w-mu)*(c.w-mu);
    #pragma unroll
    for (int o = 32; o; o >>= 1) va += __shfl_xor(va, o);
    float inv = rsqrtf(va * (1.0f / 512.0f) + 1e-5f);
    const float4* gp = (const float4*)ln_g;
    const float4* bp = (const float4*)ln_b;
    float4 g0 = gp[lane], g1 = gp[64 + lane], b0 = bp[lane], b1 = bp[64 + lane];
    ushort4* op = (ushort4*)(xn + (size_t)row * 512);
    op[lane]      = make_ushort4(f2bf((a.x-mu)*inv*g0.x + b0.x), f2bf((a.y-mu)*inv*g0.y + b0.y),
                                 f2bf((a.z-mu)*inv*g0.z + b0.z), f2bf((a.w-mu)*inv*g0.w + b0.w));
    op[64 + lane] = make_ushort4(f2bf((c.x-mu)*inv*g1.x + b1.x), f2bf((c.y-mu)*inv*g1.y + b1.y),
                                 f2bf((c.z-mu)*inv*g1.z + b1.z), f2bf((c.w-mu)*inv*g1.w + b1.w));
  } else if (bid < 4096) {
    int i = (bid - 2048) * 256 + t;
    float4 v = ((const float4*)ctx)[i];
    ((ushort4*)cb)[i] = make_ushort4(f2bf(v.x), f2bf(v.y), f2bf(v.z), f2bf(v.w));
  } else {
    int g = (bid - 4096) * 4 + (t >> 6);
    int ln = t & 63;
    int v = mask[g * 64 + ln];
    unsigned long long bb = __ballot(v != 0);
    if (ln == 0) { mb[g*2] = (unsigned)bb; mb[g*2+1] = (unsigned)(bb >> 32); }
  }
}

// ---------------- final layernorm (f32 in/out) ----------------
__global__ __launch_bounds__(256) void k_layernorm_f(
    const float* __restrict__ X, const float* __restrict__ G,
    const float* __restrict__ Bt, float* __restrict__ out)
{
  int row = blockIdx.x * 4 + (threadIdx.x >> 6);
  int lane = threadIdx.x & 63;
  const float4* xr = (const float4*)(X + (size_t)row * 512);
  float4 a = xr[lane], c = xr[64 + lane];
  float s = a.x + a.y + a.z + a.w + c.x + c.y + c.z + c.w;
  #pragma unroll
  for (int o = 32; o; o >>= 1) s += __shfl_xor(s, o);
  float mu = s * (1.0f / 512.0f);
  float va = (a.x-mu)*(a.x-mu) + (a.y-mu)*(a.y-mu) + (a.z-mu)*(a.z-mu) + (a.w-mu)*(a.w-mu)
           + (c.x-mu)*(c.x-mu) + (c.y-mu)*(c.y-mu) + (c.z-mu)*(c.z-mu) + (c.w-mu)*(c.w-mu);
  #pragma unroll
  for (int o = 32; o; o >>= 1) va += __shfl_xor(va, o);
  float inv = rsqrtf(va * (1.0f / 512.0f) + 1e-5f);
  const float4* gp = (const float4*)G;
  const float4* bp = (const float4*)Bt;
  float4 g0 = gp[lane], g1 = gp[64 + lane], b0 = bp[lane], b1 = bp[64 + lane];
  float4 y0, y1;
  y0.x = (a.x-mu)*inv*g0.x + b0.x; y0.y = (a.y-mu)*inv*g0.y + b0.y;
  y0.z = (a.z-mu)*inv*g0.z + b0.z; y0.w = (a.w-mu)*inv*g0.w + b0.w;
  y1.x = (c.x-mu)*inv*g1.x + b1.x; y1.y = (c.y-mu)*inv*g1.y + b1.y;
  y1.z = (c.z-mu)*inv*g1.z + b1.z; y1.w = (c.w-mu)*inv*g1.w + b1.w;
  float4* op = (float4*)(out + (size_t)row * 512);
  op[lane] = y0; op[64 + lane] = y1;
}

// ---------------- bf16 MFMA GEMM body: 64x128 tile, BK=64, 4 waves (2x2) ----------------
// Staging via global_load_lds (async DMA, no staging VGPRs), double-buffered LDS,
// one __syncthreads per K-step. Swizzle applied on the GLOBAL source address;
// LDS dest linear per wave (wave-uniform base + lane*16B).
// MODE 0: fragment-packed Q out. MODE 1: KV -> packed Kp (col<512) / Vp. MODE 2: f32 out.
template<int MODE>
__device__ __forceinline__ void gemm_body(
    const unsigned short* __restrict__ A, const unsigned short* __restrict__ BT,
    void* __restrict__ out0, void* __restrict__ out1, int bx, int by,
    unsigned short* smem)
{
  unsigned short* As = smem;              // [2][64*64]  = 16 KB
  unsigned short* Bs = smem + 2*64*64;    // [2][128*64] = 32 KB
  const int t = threadIdx.x;
  const int lane = t & 63, l16 = lane & 15, lhi = lane >> 4;
  const int w = t >> 6, wm = w >> 1, wn = w & 1;
  const int rowBase = by * 64;
  const int colBase = bx * 128;
  const int srr = lane >> 3, scw = lane & 7;

  f32x4 acc[2][4];
  #pragma unroll
  for (int i = 0; i < 2; i++)
    #pragma unroll
    for (int j = 0; j < 4; j++)
      acc[i][j] = f32x4{0.f, 0.f, 0.f, 0.f};

  auto STAGE = [&](int buf, int kt) {
    unsigned short* Ab = As + buf * 4096;
    unsigned short* Bb = Bs + buf * 8192;
    #pragma unroll
    for (int i = 0; i < 2; i++) {
      int rr = i * 32 + w * 8 + srr;
      stage16(A + (size_t)(rowBase + rr) * 512 + kt * 64 + ((scw ^ (rr & 7)) * 8),
              Ab + (i * 32 + w * 8) * 64);
    }
    #pragma unroll
    for (int i = 0; i < 4; i++) {
      int rr = i * 32 + w * 8 + srr;
      stage16(BT + (size_t)(colBase + rr) * 512 + kt * 64 + ((scw ^ (rr & 7)) * 8),
              Bb + (i * 32 + w * 8) * 64);
    }
  };

  STAGE(0, 0);
  __syncthreads();                         // vmcnt(0) drain + barrier: buf0 ready
  for (int kt = 0; kt < 8; ++kt) {
    const int buf = kt & 1;
    if (kt < 7) STAGE(buf ^ 1, kt + 1);    // async fill of other buffer under compute
    const char* Ab = (const char*)(As + buf * 4096);
    const char* Bb = (const char*)(Bs + buf * 8192);
    #pragma unroll
    for (int ks = 0; ks < 2; ++ks) {
      bf16x8 af[2], bb[4];
      #pragma unroll
      for (int mi = 0; mi < 2; mi++) {
        int rr = wm * 32 + mi * 16 + l16;
        int cc = ks * 4 + lhi;
        af[mi] = *(const bf16x8*)(Ab + rr * 128 + ((cc ^ (rr & 7)) * 16));
      }
      #pragma unroll
      for (int ni = 0; ni < 4; ni++) {
        int rr = wn * 64 + ni * 16 + l16;
        int cc = ks * 4 + lhi;
        bb[ni] = *(const bf16x8*)(Bb + rr * 128 + ((cc ^ (rr & 7)) * 16));
      }
      #pragma unroll
      for (int mi = 0; mi < 2; mi++)
        #pragma unroll
        for (int ni = 0; ni < 4; ni++)
          acc[mi][ni] = MFMA16(af[mi], bb[ni], acc[mi][ni]);
    }
    __syncthreads();                       // drains staged loads; buf^1 ready next iter
  }

  if constexpr (MODE == 2) {
    const int r0 = rowBase + wm * 32 + lhi * 4;
    const int c0 = colBase + wn * 64 + l16;
    #pragma unroll
    for (int mi = 0; mi < 2; mi++)
      #pragma unroll
      for (int ni = 0; ni < 4; ni++)
        #pragma unroll
        for (int r = 0; r < 4; r++)
          ((float*)out0)[(size_t)(r0 + mi * 16 + r) * 512 + c0 + ni * 16] = acc[mi][ni][r];
  } else {
    // stage 64x128 packed tile (4 regions x 2048 shorts = 16 KB) in LDS, then coalesced write
    unsigned short* stg = smem;
    const bool isV = (MODE == 1) && (colBase >= 512);
    if (!isV) {
      #pragma unroll
      for (int mi = 0; mi < 2; mi++) {
        int rl = wm * 32 + mi * 16 + lhi * 4;
        int tl = rl >> 5;
        #pragma unroll
        for (int ni = 0; ni < 4; ni++) {
          int cl = wn * 64 + ni * 16 + l16;
          int hl = cl >> 6, d = cl & 63;
          int rbase = (hl * 2 + tl) * 2048 + (d >> 4) * 512 + 256 * ((d >> 3) & 1) + (d & 7);
          #pragma unroll
          for (int r = 0; r < 4; r++)
            stg[rbase + ((rl + r) & 31) * 8] = f2bf(acc[mi][ni][r]);
        }
      }
    } else {
      #pragma unroll
      for (int mi = 0; mi < 2; mi++) {
        int rl = wm * 32 + mi * 16 + lhi * 4;
        int tl = rl >> 5, kvr = rl & 31;
        #pragma unroll
        for (int ni = 0; ni < 4; ni++) {
          int cl = wn * 64 + ni * 16 + l16;
          int hl = cl >> 6, d = cl & 63;
          int off = (hl * 2 + tl) * 2048 + (d >> 5) * 1024 + ((kvr >> 4) & 1) * 512
                  + ((d & 31) + 32 * ((kvr >> 3) & 1)) * 8 + (kvr & 7);
          ushort4 p = make_ushort4(f2bf(acc[mi][ni][0]), f2bf(acc[mi][ni][1]),
                                   f2bf(acc[mi][ni][2]), f2bf(acc[mi][ni][3]));
          *(ushort4*)(stg + off) = p;
        }
      }
    }
    __syncthreads();
    const int bb2 = rowBase >> 11;
    const int hh0 = (colBase & 511) >> 6;
    const int tile0 = (rowBase & 2047) >> 5;
    unsigned short* gout = (unsigned short*)(isV ? out1 : out0);
    #pragma unroll
    for (int ridx = 0; ridx < 4; ridx++) {
      int hl = ridx >> 1, tl = ridx & 1;
      size_t gb = ((size_t)((bb2 * 8 + hh0 + hl) * 64 + tile0 + tl)) * 2048 + t * 8;
      *(uint4*)(gout + gb) = *(const uint4*)(stg + ridx * 2048 + t * 8);
    }
  }
}

// 768 blocks: xcd = bid&7 owns M-stripe of 512 rows (8 mtiles x 12 coltiles).
__global__ __launch_bounds__(256, 2) void k_qkv(
    const unsigned short* __restrict__ xn, const unsigned short* __restrict__ WqT,
    unsigned short* __restrict__ Qp,
    const unsigned short* __restrict__ cb, const unsigned short* __restrict__ WkvT,
    unsigned short* __restrict__ Kp, unsigned short* __restrict__ Vp)
{
  __shared__ __align__(16) unsigned short smem[2*64*64 + 2*128*64];
  const int bid = blockIdx.x;
  const int xcd = bid & 7, loc = bid >> 3;
  const int mloc = loc / 12, ct = loc % 12;
  const int mtile = xcd * 8 + mloc;
  if (ct < 4) gemm_body<0>(xn, WqT, Qp, nullptr, ct, mtile, smem);
  else        gemm_body<1>(cb, WkvT, Kp, Vp, ct - 4, mtile, smem);
}

// 256 blocks: xcd stripe, 8 mtiles x 4 coltiles per xcd.
__global__ __launch_bounds__(256, 2) void k_oproj(
    const unsigned short* __restrict__ ao, const unsigned short* __restrict__ WoT,
    float* __restrict__ proj)
{
  __shared__ __align__(16) unsigned short smem[2*64*64 + 2*128*64];
  const int bid = blockIdx.x;
  const int xcd = bid & 7, loc = bid >> 3;
  const int mloc = loc >> 2, ct = loc & 3;
  const int mtile = xcd * 8 + mloc;
  gemm_body<2>(ao, WoT, proj, nullptr, ct, mtile, smem);
}

// ---------------- flash attention v8: 2 q-tiles per wave (halved KV L2 traffic) ----------------
// 512 blocks, 4 waves; XCD decode keeps 2 bh per XCD. Wave w streams kv quarter
// [w*512, +512) ONCE and applies each K/V fragment to TWO q-tiles (qtA, qtB).
// 4-way merge runs twice, reusing mbuf with a barrier between passes.
__global__ __launch_bounds__(256, 2) void k_attn(
    const unsigned short* __restrict__ Qp, const unsigned short* __restrict__ Kp,
    const unsigned short* __restrict__ Vp, const unsigned int* __restrict__ mb,
    unsigned short* __restrict__ O)
{
  __shared__ __align__(16) float mbuf[3][64][34];   // acc(32) + m + l per lane
  const int t = threadIdx.x, lane = t & 63, q5 = lane & 31, hi = lane >> 5;
  const int w = t >> 6;
  const int bid = blockIdx.x;
  const int bh = (bid & 7) * 2 + (bid >> 8);        // XCD-local bh pair
  const int g = (bid >> 3) & 31;
  const int qtA = g * 2, qtB = g * 2 + 1;
  const int b = bh >> 3, h = bh & 7;
  const float C2f = 0.022542110013890053f;          // SCALE^2 * log2(e)

  bf16x8 qfA[4], qfB[4];
  {
    const unsigned short* qpA = Qp + (size_t)(bh * 64 + qtA) * 2048 + lane * 8;
    const unsigned short* qpB = Qp + (size_t)(bh * 64 + qtB) * 2048 + lane * 8;
    #pragma unroll
    for (int kk = 0; kk < 4; kk++) { qfA[kk] = *(const bf16x8*)(qpA + kk * 512);
                                     qfB[kk] = *(const bf16x8*)(qpB + kk * 512); }
  }
  const unsigned short* kpb = Kp + (size_t)bh * 131072 + lane * 8;
  const unsigned short* vpb = Vp + (size_t)bh * 131072 + lane * 8;
  const unsigned int* mbp = mb + b * 64;

  float mrunA = -3e38f, lrunA = 0.f;                // lrun: PER-LANE partials
  float mrunB = -3e38f, lrunB = 0.f;
  f32x16 accA0, accA1, accB0, accB1;
  #pragma unroll
  for (int i = 0; i < 16; i++) { accA0[i] = 0.f; accA1[i] = 0.f; accB0[i] = 0.f; accB1[i] = 0.f; }

  bf16x8 kf[4], vf[4];
  auto loadK = [&](int tile) {
    #pragma unroll
    for (int kk = 0; kk < 4; kk++)
      kf[kk] = *(const bf16x8*)(kpb + (size_t)tile * 2048 + kk * 512);
  };
  auto loadV = [&](int tile) {
    #pragma unroll
    for (int i = 0; i < 4; i++)
      vf[i] = *(const bf16x8*)(vpb + (size_t)tile * 2048 + i * 512);
  };

  // softmax + PV for one q-tile (sX consumed; acc/m/l updated in place)
  auto smax_pv = [&](f32x16& sX, float& mrun, float& lrun, f32x16& a0, f32x16& a1,
                     unsigned mh) {
    float m0 = fmaxf(fmaxf(sX[0], sX[1]),  fmaxf(sX[2], sX[3]));
    float m1 = fmaxf(fmaxf(sX[4], sX[5]),  fmaxf(sX[6], sX[7]));
    float m2 = fmaxf(fmaxf(sX[8], sX[9]),  fmaxf(sX[10], sX[11]));
    float m3 = fmaxf(fmaxf(sX[12], sX[13]), fmaxf(sX[14], sX[15]));
    float tmax = fmaxf(fmaxf(m0, m1), fmaxf(m2, m3));
    tmax = xpair_max(tmax);
    if (!__all(tmax <= mrun + 400.f)) {             // defer-max: rare
      float mnew = fmaxf(mrun, tmax);
      float sf = fexp2((mrun - mnew) * C2f);
      lrun *= sf;
      #pragma unroll
      for (int i = 0; i < 16; i++) { a0[i] *= sf; a1[i] *= sf; }
      mrun = mnew;
    }
    float nb = -mrun * C2f;
    float p[16];
    #pragma unroll
    for (int r = 0; r < 16; r++) {
      float pv = fexp2(fmaf(sX[r], C2f, nb));
      p[r] = ((mh >> ((r & 3) + 8 * (r >> 2))) & 1u) ? pv : 0.f;
    }
    float rsa = (p[0] + p[1]) + (p[2] + p[3]);
    float rsb = (p[4] + p[5]) + (p[6] + p[7]);
    float rsc = (p[8] + p[9]) + (p[10] + p[11]);
    float rsd = (p[12] + p[13]) + (p[14] + p[15]);
    lrun += (rsa + rsb) + (rsc + rsd);              // per-lane partial

    unsigned wd[8];
    #pragma unroll
    for (int i = 0; i < 8; i++) wd[i] = cvtpk(p[2 * i], p[2 * i + 1]);
    plswap(wd[0], wd[2]); plswap(wd[1], wd[3]);
    plswap(wd[4], wd[6]); plswap(wd[5], wd[7]);
    union { unsigned u[4]; bf16x8 v; } U0, U1;
    U0.u[0] = wd[0]; U0.u[1] = wd[1]; U0.u[2] = wd[2]; U0.u[3] = wd[3];
    U1.u[0] = wd[4]; U1.u[1] = wd[5]; U1.u[2] = wd[6]; U1.u[3] = wd[7];

    __builtin_amdgcn_s_setprio(1);
    a0 = MFMA32(vf[0], U0.v, a0);
    a0 = MFMA32(vf[1], U1.v, a0);
    a1 = MFMA32(vf[2], U0.v, a1);
    a1 = MFMA32(vf[3], U1.v, a1);
    __builtin_amdgcn_s_setprio(0);
  };

  const int tb = w * 16;
  loadK(tb); loadV(tb);
  for (int it = 0; it < 16; ++it) {
    const int ti = tb + it;

    // ---- QK^T for both q-tiles (kf reused 2x) ----
    f32x16 sA, sB;
    #pragma unroll
    for (int i = 0; i < 16; i++) { sA[i] = 0.f; sB[i] = 0.f; }
    __builtin_amdgcn_s_setprio(1);
    #pragma unroll
    for (int kk = 0; kk < 4; kk++) sA = MFMA32(kf[kk], qfA[kk], sA);
    #pragma unroll
    for (int kk = 0; kk < 4; kk++) sB = MFMA32(kf[kk], qfB[kk], sB);
    __builtin_amdgcn_s_setprio(0);
    if (it < 15) loadK(ti + 1);          // kf dead: prefetch under softmax+PV

    unsigned mh = mbp[ti] >> (hi * 4);   // mask depends only on kv: shared by A,B
    smax_pv(sA, mrunA, lrunA, accA0, accA1, mh);
    smax_pv(sB, mrunB, lrunB, accB0, accB1, mh);
    if (it < 15) loadV(ti + 1);          // vf dead: prefetch under next QK+softmax
  }

  // ---- 4-way merge, twice (A then B), reusing mbuf ----
  auto merge_write = [&](f32x16& a0, f32x16& a1, float mr, float lr, int qt) {
    if (w) {
      #pragma unroll
      for (int i = 0; i < 16; i++) { mbuf[w-1][lane][i] = a0[i]; mbuf[w-1][lane][16 + i] = a1[i]; }
      mbuf[w-1][lane][32] = mr; mbuf[w-1][lane][33] = lr;
    }
    __syncthreads();
    if (!w) {
      float mo[3], lo[3];
      #pragma unroll
      for (int wv = 0; wv < 3; wv++) { mo[wv] = mbuf[wv][lane][32]; lo[wv] = mbuf[wv][lane][33]; }
      float mN = fmaxf(fmaxf(mr, mo[0]), fmaxf(mo[1], mo[2]));
      float sf0 = fexp2((mr - mN) * C2f);
      float sfv[3];
      float lsum = lr * sf0;
      #pragma unroll
      for (int wv = 0; wv < 3; wv++) { sfv[wv] = fexp2((mo[wv] - mN) * C2f); lsum += lo[wv] * sfv[wv]; }
      lsum = xpair_sum(lsum);                       // complete row sum across lane pair
      float linv = 1.f / lsum;
      float a2[32];
      #pragma unroll
      for (int i = 0; i < 16; i++) {
        float v0 = a0[i] * sf0, v1 = a1[i] * sf0;
        #pragma unroll
        for (int wv = 0; wv < 3; wv++) {
          v0 += mbuf[wv][lane][i] * sfv[wv];
          v1 += mbuf[wv][lane][16 + i] * sfv[wv];
        }
        a2[i] = v0 * linv;
        a2[16 + i] = v1 * linv;
      }
      // transpose O^T[d][q] -> O[q][d] via LDS (stride 72 shorts, 16B-aligned rows)
      unsigned short* ot = (unsigned short*)&mbuf[0][0][0];
      #pragma unroll
      for (int d2 = 0; d2 < 2; d2++)
        #pragma unroll
        for (int i = 0; i < 8; i++) {
          int d0 = ((2 * i) & 3) + 8 * (i >> 1) + 4 * hi + 32 * d2;
          unsigned wv2 = cvtpk(a2[d2 * 16 + 2 * i], a2[d2 * 16 + 2 * i + 1]);
          *(unsigned*)(ot + q5 * 72 + d0) = wv2;
        }
      #pragma unroll
      for (int it2 = 0; it2 < 4; ++it2) {
        int row = (lane >> 3) + it2 * 8, ch = lane & 7;
        uint4 val = *(const uint4*)(ot + row * 72 + ch * 8);
        *(uint4*)(O + ((size_t)(b * 2048 + qt * 32 + row)) * 512 + h * 64 + ch * 8) = val;
      }
    }
    __syncthreads();                                // mbuf free for next pass
  };
  merge_write(accA0, accA1, mrunA, lrunA, qtA);
  merge_write(accB0, accB1, mrunB, lrunB, qtB);
}

// ---------------- host ----------------
extern "C" void kernel_launch(void* const* d_in, const int* in_sizes, int n_in,
                              void* d_out, int out_size, void* d_ws, size_t ws_size,
                              hipStream_t stream) {
  const float* x     = (const float*)d_in[0];
  const float* ctx   = (const float*)d_in[1];
  const int*   mask  = (const int*)d_in[2];
  const float* ln_g  = (const float*)d_in[3];
  const float* ln_b  = (const float*)d_in[4];
  const float* Wq    = (const float*)d_in[5];
  const float* Wkv   = (const float*)d_in[6];
  const float* Wo    = (const float*)d_in[7];
  const float* lno_g = (const float*)d_in[8];
  const float* lno_b = (const float*)d_in[9];
  float* out = (float*)d_out;

  char* ws = (char*)d_ws;
  unsigned short* WqT  = (unsigned short*)(ws + 0);                         // 512 KB
  unsigned short* WkvT = (unsigned short*)(ws + (size_t)1 * (1 << 19));     // 1 MB
  unsigned short* WoT  = (unsigned short*)(ws + (size_t)3 * (1 << 19));     // 512 KB
  unsigned short* xn   = (unsigned short*)(ws + (size_t)2  * (1 << 20));    // 4 MB
  unsigned short* cb   = (unsigned short*)(ws + (size_t)6  * (1 << 20));    // 4 MB
  unsigned short* Qp   = (unsigned short*)(ws + (size_t)10 * (1 << 20));    // 4 MB (fragment-packed)
  unsigned short* Kp   = (unsigned short*)(ws + (size_t)14 * (1 << 20));    // 4 MB (fragment-packed)
  unsigned short* Vp   = (unsigned short*)(ws + (size_t)18 * (1 << 20));    // 4 MB (fragment-packed)
  unsigned short* ao   = (unsigned short*)(ws + (size_t)22 * (1 << 20));    // 4 MB
  float* proj          = (float*)(ws + (size_t)26 * (1 << 20));             // 8 MB
  unsigned int* mbw    = (unsigned int*)(ws + (size_t)26 * (1 << 20));      // 512 B, overlaps proj (dead by then)

  k_prep<<<4112, 256, 0, stream>>>(Wq, Wkv, Wo, x, ln_g, ln_b, ctx, mask,
                                   WqT, WkvT, WoT, xn, cb, mbw);
  k_qkv<<<768, 256, 0, stream>>>(xn, WqT, Qp, cb, WkvT, Kp, Vp);
  k_attn<<<512, 256, 0, stream>>>(Qp, Kp, Vp, mbw, ao);
  k_oproj<<<256, 256, 0, stream>>>(ao, WoT, proj);
  k_layernorm_f<<<1024, 256, 0, stream>>>(proj, lno_g, lno_b, out);
}

// Round 12
// 60.090 us; speedup vs baseline: 1.5250x; 1.0264x over previous
//
#include <hip/hip_runtime.h>
#include <stdint.h>

typedef float f32x4 __attribute__((ext_vector_type(4)));
typedef float f32x16 __attribute__((ext_vector_type(16)));
typedef __bf16 bf16x8 __attribute__((ext_vector_type(8)));
typedef unsigned int uint2v __attribute__((ext_vector_type(2)));

#define MFMA16(a,b,c) __builtin_amdgcn_mfma_f32_16x16x32_bf16((a),(b),(c),0,0,0)
#define MFMA32(a,b,c) __builtin_amdgcn_mfma_f32_32x32x16_bf16((a),(b),(c),0,0,0)

__device__ __forceinline__ unsigned short f2bf(float f){
  unsigned int u = __float_as_uint(f);
  u += 0x7FFFu + ((u >> 16) & 1u);
  return (unsigned short)(u >> 16);
}

__device__ __forceinline__ unsigned cvtpk(float lo, float hi){
  unsigned r;
  asm volatile("v_cvt_pk_bf16_f32 %0, %1, %2" : "=v"(r) : "v"(lo), "v"(hi));
  return r;
}

__device__ __forceinline__ float fexp2(float x){
#if __has_builtin(__builtin_amdgcn_exp2f)
  return __builtin_amdgcn_exp2f(x);
#else
  return exp2f(x);
#endif
}

__device__ __forceinline__ void plswap(unsigned &a, unsigned &b){
#if __has_builtin(__builtin_amdgcn_permlane32_swap)
  uint2v r = __builtin_amdgcn_permlane32_swap(a, b, false, false);
  a = r[0]; b = r[1];
#else
  unsigned xa = __shfl_xor(a, 32), xb = __shfl_xor(b, 32);
  int hi = (threadIdx.x & 63) >> 5;
  unsigned na = hi ? xb : a;
  unsigned nb = hi ? b : xa;
  a = na; b = nb;
#endif
}

// pairwise (lane, lane^32) max / sum via permlane32_swap — pure VALU, no LDS
__device__ __forceinline__ float xpair_max(float x){
  unsigned a = __float_as_uint(x), b = a;
  plswap(a, b);
  return fmaxf(__uint_as_float(a), __uint_as_float(b));
}
__device__ __forceinline__ float xpair_sum(float x){
  unsigned a = __float_as_uint(x), b = a;
  plswap(a, b);
  return __uint_as_float(a) + __uint_as_float(b);
}

// async global -> LDS, 16B per lane; LDS dest is wave-uniform base + lane*16
__device__ __forceinline__ void stage16(const unsigned short* g, unsigned short* l){
  __builtin_amdgcn_global_load_lds(
      (const __attribute__((address_space(1))) void*)g,
      (__attribute__((address_space(3))) void*)l, 16, 0, 0);
}

// ---------------- prep router: weight transposes + LN(x) + cast(ctx) + mask bias frags ----------------
__global__ __launch_bounds__(256) void k_prep(
    const float* __restrict__ Wq, const float* __restrict__ Wkv, const float* __restrict__ Wo,
    const float* __restrict__ x, const float* __restrict__ ln_g, const float* __restrict__ ln_b,
    const float* __restrict__ ctx, const int* __restrict__ mask,
    unsigned short* __restrict__ WqT, unsigned short* __restrict__ WkvT, unsigned short* __restrict__ WoT,
    unsigned short* __restrict__ xn, unsigned short* __restrict__ cb, unsigned short* __restrict__ kbias)
{
  __shared__ float tile[32][33];
  const int bid = blockIdx.x, t = threadIdx.x;
  if (bid < 1024) {
    const float* W; unsigned short* WT; int N, bx, by;
    if (bid < 256)      { W = Wq;  WT = WqT;  N = 512;  bx = bid & 15;        by = bid >> 4; }
    else if (bid < 768) { W = Wkv; WT = WkvT; N = 1024; bx = (bid-256) & 31;  by = (bid-256) >> 5; }
    else                { W = Wo;  WT = WoT;  N = 512;  bx = (bid-768) & 15;  by = (bid-768) >> 4; }
    const int tx = t & 31, ty = t >> 5;
    #pragma unroll
    for (int i = 0; i < 4; i++)
      tile[ty + i*8][tx] = W[(size_t)(by*32 + ty + i*8) * N + bx*32 + tx];
    __syncthreads();
    #pragma unroll
    for (int i = 0; i < 4; i++)
      WT[(size_t)(bx*32 + ty + i*8) * 512 + by*32 + tx] = f2bf(tile[tx][ty + i*8]);
  } else if (bid < 2048) {
    int row = (bid - 1024) * 4 + (t >> 6);
    int lane = t & 63;
    const float4* xr = (const float4*)(x + (size_t)row * 512);
    float4 a = xr[lane], c = xr[64 + lane];
    float s = a.x + a.y + a.z + a.w + c.x + c.y + c.z + c.w;
    #pragma unroll
    for (int o = 32; o; o >>= 1) s += __shfl_xor(s, o);
    float mu = s * (1.0f / 512.0f);
    float va = (a.x-mu)*(a.x-mu) + (a.y-mu)*(a.y-mu) + (a.z-mu)*(a.z-mu) + (a.w-mu)*(a.w-mu)
             + (c.x-mu)*(c.x-mu) + (c.y-mu)*(c.y-mu) + (c.z-mu)*(c.z-mu) + (c.w-mu)*(c.w-mu);
    #pragma unroll
    for (int o = 32; o; o >>= 1) va += __shfl_xor(va, o);
    float inv = rsqrtf(va * (1.0f / 512.0f) + 1e-5f);
    const float4* gp = (const float4*)ln_g;
    const float4* bp = (const float4*)ln_b;
    float4 g0 = gp[lane], g1 = gp[64 + lane], b0 = bp[lane], b1 = bp[64 + lane];
    ushort4* op = (ushort4*)(xn + (size_t)row * 512);
    op[lane]      = make_ushort4(f2bf((a.x-mu)*inv*g0.x + b0.x), f2bf((a.y-mu)*inv*g0.y + b0.y),
                                 f2bf((a.z-mu)*inv*g0.z + b0.z), f2bf((a.w-mu)*inv*g0.w + b0.w));
    op[64 + lane] = make_ushort4(f2bf((c.x-mu)*inv*g1.x + b1.x), f2bf((c.y-mu)*inv*g1.y + b1.y),
                                 f2bf((c.z-mu)*inv*g1.z + b1.z), f2bf((c.w-mu)*inv*g1.w + b1.w));
  } else if (bid < 4096) {
    int i = (bid - 2048) * 256 + t;
    float4 v = ((const float4*)ctx)[i];
    ((ushort4*)cb)[i] = make_ushort4(f2bf(v.x), f2bf(v.y), f2bf(v.z), f2bf(v.w));
  } else {
    // mask -> MFMA A-operand bias fragments: per (b, kv-tile) 32x16 bf16, k=0 slice = bias[kv]
    int i = (bid - 4096) * 256 + t;            // 4096 threads, one per (b,kv)
    int b2 = i >> 11, kv = i & 2047;
    int tl = kv >> 5, ln = kv & 31;
    unsigned short bias = (mask[b2 * 2048 + kv] != 0) ? (unsigned short)0 : f2bf(-1e6f);
    ushort4* p0 = (ushort4*)(kbias + ((size_t)((b2 * 64 + tl) * 64 + ln)) * 8);
    p0[0] = make_ushort4(bias, 0, 0, 0);
    p0[1] = make_ushort4(0, 0, 0, 0);
    ushort4* p1 = (ushort4*)(kbias + ((size_t)((b2 * 64 + tl) * 64 + ln + 32)) * 8);
    p1[0] = make_ushort4(0, 0, 0, 0);
    p1[1] = make_ushort4(0, 0, 0, 0);
  }
}

// ---------------- final layernorm (f32 in/out) ----------------
__global__ __launch_bounds__(256) void k_layernorm_f(
    const float* __restrict__ X, const float* __restrict__ G,
    const float* __restrict__ Bt, float* __restrict__ out)
{
  int row = blockIdx.x * 4 + (threadIdx.x >> 6);
  int lane = threadIdx.x & 63;
  const float4* xr = (const float4*)(X + (size_t)row * 512);
  float4 a = xr[lane], c = xr[64 + lane];
  float s = a.x + a.y + a.z + a.w + c.x + c.y + c.z + c.w;
  #pragma unroll
  for (int o = 32; o; o >>= 1) s += __shfl_xor(s, o);
  float mu = s * (1.0f / 512.0f);
  float va = (a.x-mu)*(a.x-mu) + (a.y-mu)*(a.y-mu) + (a.z-mu)*(a.z-mu) + (a.w-mu)*(a.w-mu)
           + (c.x-mu)*(c.x-mu) + (c.y-mu)*(c.y-mu) + (c.z-mu)*(c.z-mu) + (c.w-mu)*(c.w-mu);
  #pragma unroll
  for (int o = 32; o; o >>= 1) va += __shfl_xor(va, o);
  float inv = rsqrtf(va * (1.0f / 512.0f) + 1e-5f);
  const float4* gp = (const float4*)G;
  const float4* bp = (const float4*)Bt;
  float4 g0 = gp[lane], g1 = gp[64 + lane], b0 = bp[lane], b1 = bp[64 + lane];
  float4 y0, y1;
  y0.x = (a.x-mu)*inv*g0.x + b0.x; y0.y = (a.y-mu)*inv*g0.y + b0.y;
  y0.z = (a.z-mu)*inv*g0.z + b0.z; y0.w = (a.w-mu)*inv*g0.w + b0.w;
  y1.x = (c.x-mu)*inv*g1.x + b1.x; y1.y = (c.y-mu)*inv*g1.y + b1.y;
  y1.z = (c.z-mu)*inv*g1.z + b1.z; y1.w = (c.w-mu)*inv*g1.w + b1.w;
  float4* op = (float4*)(out + (size_t)row * 512);
  op[lane] = y0; op[64 + lane] = y1;
}

// ---------------- bf16 MFMA GEMM body: 64x128 tile, BK=64, 4 waves (2x2) ----------------
// Staging via global_load_lds (async DMA, no staging VGPRs), double-buffered LDS,
// one __syncthreads per K-step. Swizzle applied on the GLOBAL source address;
// LDS dest linear per wave (wave-uniform base + lane*16B).
// MODE 0: fragment-packed Q out. MODE 1: KV -> packed Kp (col<512) / Vp. MODE 2: f32 out.
template<int MODE>
__device__ __forceinline__ void gemm_body(
    const unsigned short* __restrict__ A, const unsigned short* __restrict__ BT,
    void* __restrict__ out0, void* __restrict__ out1, int bx, int by,
    unsigned short* smem)
{
  unsigned short* As = smem;              // [2][64*64]  = 16 KB
  unsigned short* Bs = smem + 2*64*64;    // [2][128*64] = 32 KB
  const int t = threadIdx.x;
  const int lane = t & 63, l16 = lane & 15, lhi = lane >> 4;
  const int w = t >> 6, wm = w >> 1, wn = w & 1;
  const int rowBase = by * 64;
  const int colBase = bx * 128;
  const int srr = lane >> 3, scw = lane & 7;

  f32x4 acc[2][4];
  #pragma unroll
  for (int i = 0; i < 2; i++)
    #pragma unroll
    for (int j = 0; j < 4; j++)
      acc[i][j] = f32x4{0.f, 0.f, 0.f, 0.f};

  auto STAGE = [&](int buf, int kt) {
    unsigned short* Ab = As + buf * 4096;
    unsigned short* Bb = Bs + buf * 8192;
    #pragma unroll
    for (int i = 0; i < 2; i++) {
      int rr = i * 32 + w * 8 + srr;
      stage16(A + (size_t)(rowBase + rr) * 512 + kt * 64 + ((scw ^ (rr & 7)) * 8),
              Ab + (i * 32 + w * 8) * 64);
    }
    #pragma unroll
    for (int i = 0; i < 4; i++) {
      int rr = i * 32 + w * 8 + srr;
      stage16(BT + (size_t)(colBase + rr) * 512 + kt * 64 + ((scw ^ (rr & 7)) * 8),
              Bb + (i * 32 + w * 8) * 64);
    }
  };

  STAGE(0, 0);
  __syncthreads();                         // vmcnt(0) drain + barrier: buf0 ready
  for (int kt = 0; kt < 8; ++kt) {
    const int buf = kt & 1;
    if (kt < 7) STAGE(buf ^ 1, kt + 1);    // async fill of other buffer under compute
    const char* Ab = (const char*)(As + buf * 4096);
    const char* Bb = (const char*)(Bs + buf * 8192);
    #pragma unroll
    for (int ks = 0; ks < 2; ++ks) {
      bf16x8 af[2], bb[4];
      #pragma unroll
      for (int mi = 0; mi < 2; mi++) {
        int rr = wm * 32 + mi * 16 + l16;
        int cc = ks * 4 + lhi;
        af[mi] = *(const bf16x8*)(Ab + rr * 128 + ((cc ^ (rr & 7)) * 16));
      }
      #pragma unroll
      for (int ni = 0; ni < 4; ni++) {
        int rr = wn * 64 + ni * 16 + l16;
        int cc = ks * 4 + lhi;
        bb[ni] = *(const bf16x8*)(Bb + rr * 128 + ((cc ^ (rr & 7)) * 16));
      }
      #pragma unroll
      for (int mi = 0; mi < 2; mi++)
        #pragma unroll
        for (int ni = 0; ni < 4; ni++)
          acc[mi][ni] = MFMA16(af[mi], bb[ni], acc[mi][ni]);
    }
    __syncthreads();                       // drains staged loads; buf^1 ready next iter
  }

  if constexpr (MODE == 2) {
    const int r0 = rowBase + wm * 32 + lhi * 4;
    const int c0 = colBase + wn * 64 + l16;
    #pragma unroll
    for (int mi = 0; mi < 2; mi++)
      #pragma unroll
      for (int ni = 0; ni < 4; ni++)
        #pragma unroll
        for (int r = 0; r < 4; r++)
          ((float*)out0)[(size_t)(r0 + mi * 16 + r) * 512 + c0 + ni * 16] = acc[mi][ni][r];
  } else {
    // stage 64x128 packed tile (4 regions x 2048 shorts = 16 KB) in LDS, then coalesced write
    unsigned short* stg = smem;
    const bool isV = (MODE == 1) && (colBase >= 512);
    if (!isV) {
      #pragma unroll
      for (int mi = 0; mi < 2; mi++) {
        int rl = wm * 32 + mi * 16 + lhi * 4;
        int tl = rl >> 5;
        #pragma unroll
        for (int ni = 0; ni < 4; ni++) {
          int cl = wn * 64 + ni * 16 + l16;
          int hl = cl >> 6, d = cl & 63;
          int rbase = (hl * 2 + tl) * 2048 + (d >> 4) * 512 + 256 * ((d >> 3) & 1) + (d & 7);
          #pragma unroll
          for (int r = 0; r < 4; r++)
            stg[rbase + ((rl + r) & 31) * 8] = f2bf(acc[mi][ni][r]);
        }
      }
    } else {
      #pragma unroll
      for (int mi = 0; mi < 2; mi++) {
        int rl = wm * 32 + mi * 16 + lhi * 4;
        int tl = rl >> 5, kvr = rl & 31;
        #pragma unroll
        for (int ni = 0; ni < 4; ni++) {
          int cl = wn * 64 + ni * 16 + l16;
          int hl = cl >> 6, d = cl & 63;
          int off = (hl * 2 + tl) * 2048 + (d >> 5) * 1024 + ((kvr >> 4) & 1) * 512
                  + ((d & 31) + 32 * ((kvr >> 3) & 1)) * 8 + (kvr & 7);
          ushort4 p = make_ushort4(f2bf(acc[mi][ni][0]), f2bf(acc[mi][ni][1]),
                                   f2bf(acc[mi][ni][2]), f2bf(acc[mi][ni][3]));
          *(ushort4*)(stg + off) = p;
        }
      }
    }
    __syncthreads();
    const int bb2 = rowBase >> 11;
    const int hh0 = (colBase & 511) >> 6;
    const int tile0 = (rowBase & 2047) >> 5;
    unsigned short* gout = (unsigned short*)(isV ? out1 : out0);
    #pragma unroll
    for (int ridx = 0; ridx < 4; ridx++) {
      int hl = ridx >> 1, tl = ridx & 1;
      size_t gb = ((size_t)((bb2 * 8 + hh0 + hl) * 64 + tile0 + tl)) * 2048 + t * 8;
      *(uint4*)(gout + gb) = *(const uint4*)(stg + ridx * 2048 + t * 8);
    }
  }
}

// 768 blocks: xcd = bid&7 owns M-stripe of 512 rows (8 mtiles x 12 coltiles).
__global__ __launch_bounds__(256, 2) void k_qkv(
    const unsigned short* __restrict__ xn, const unsigned short* __restrict__ WqT,
    unsigned short* __restrict__ Qp,
    const unsigned short* __restrict__ cb, const unsigned short* __restrict__ WkvT,
    unsigned short* __restrict__ Kp, unsigned short* __restrict__ Vp)
{
  __shared__ __align__(16) unsigned short smem[2*64*64 + 2*128*64];
  const int bid = blockIdx.x;
  const int xcd = bid & 7, loc = bid >> 3;
  const int mloc = loc / 12, ct = loc % 12;
  const int mtile = xcd * 8 + mloc;
  if (ct < 4) gemm_body<0>(xn, WqT, Qp, nullptr, ct, mtile, smem);
  else        gemm_body<1>(cb, WkvT, Kp, Vp, ct - 4, mtile, smem);
}

// 256 blocks: xcd stripe, 8 mtiles x 4 coltiles per xcd.
__global__ __launch_bounds__(256, 2) void k_oproj(
    const unsigned short* __restrict__ ao, const unsigned short* __restrict__ WoT,
    float* __restrict__ proj)
{
  __shared__ __align__(16) unsigned short smem[2*64*64 + 2*128*64];
  const int bid = blockIdx.x;
  const int xcd = bid & 7, loc = bid >> 3;
  const int mloc = loc >> 2, ct = loc & 3;
  const int mtile = xcd * 8 + mloc;
  gemm_body<2>(ao, WoT, proj, nullptr, ct, mtile, smem);
}

// ---------------- flash attention v9: v8 + mask/init folded into MFMA bias ----------------
// 512 blocks, 4 waves; 2 q-tiles per wave (halved KV L2 traffic). Per kv-tile:
// sbias = MFMA(kbias_frag, e0, 0) computes S=bias[kv] (0 or -1e6) ONCE; both q-tiles'
// QK chains start from sbias. No per-element mask decode, no s-init movs, no selects:
// p = exp2(fma(s,C2f,nb)) underflows to exact 0 for masked columns.
__global__ __launch_bounds__(256, 2) void k_attn(
    const unsigned short* __restrict__ Qp, const unsigned short* __restrict__ Kp,
    const unsigned short* __restrict__ Vp, const unsigned short* __restrict__ KB,
    unsigned short* __restrict__ O)
{
  __shared__ __align__(16) float mbuf[3][64][34];   // acc(32) + m + l per lane
  const int t = threadIdx.x, lane = t & 63, q5 = lane & 31, hi = lane >> 5;
  const int w = t >> 6;
  const int bid = blockIdx.x;
  const int bh = (bid & 7) * 2 + (bid >> 8);        // XCD-local bh pair
  const int g = (bid >> 3) & 31;
  const int qtA = g * 2, qtB = g * 2 + 1;
  const int b = bh >> 3, h = bh & 7;
  const float C2f = 0.022542110013890053f;          // SCALE^2 * log2(e)

  bf16x8 qfA[4], qfB[4];
  {
    const unsigned short* qpA = Qp + (size_t)(bh * 64 + qtA) * 2048 + lane * 8;
    const unsigned short* qpB = Qp + (size_t)(bh * 64 + qtB) * 2048 + lane * 8;
    #pragma unroll
    for (int kk = 0; kk < 4; kk++) { qfA[kk] = *(const bf16x8*)(qpA + kk * 512);
                                     qfB[kk] = *(const bf16x8*)(qpB + kk * 512); }
  }
  const unsigned short* kpb = Kp + (size_t)bh * 131072 + lane * 8;
  const unsigned short* vpb = Vp + (size_t)bh * 131072 + lane * 8;
  const unsigned short* kbb = KB + (size_t)b * 32768 + lane * 8;

  // constant B-operand e0: B[k=0][q]=1, else 0  (lane<32 -> elem0 = bf16 1.0)
  union { unsigned u[4]; bf16x8 v; } QB;
  QB.u[0] = (lane < 32) ? 0x00003F80u : 0u;
  QB.u[1] = 0u; QB.u[2] = 0u; QB.u[3] = 0u;
  f32x16 zv;
  #pragma unroll
  for (int i = 0; i < 16; i++) zv[i] = 0.f;

  float mrunA = -3e38f, lrunA = 0.f;                // lrun: PER-LANE partials
  float mrunB = -3e38f, lrunB = 0.f;
  f32x16 accA0, accA1, accB0, accB1;
  #pragma unroll
  for (int i = 0; i < 16; i++) { accA0[i] = 0.f; accA1[i] = 0.f; accB0[i] = 0.f; accB1[i] = 0.f; }

  bf16x8 kf[4], vf[4], kbf;
  auto loadK = [&](int tile) {
    #pragma unroll
    for (int kk = 0; kk < 4; kk++)
      kf[kk] = *(const bf16x8*)(kpb + (size_t)tile * 2048 + kk * 512);
    kbf = *(const bf16x8*)(kbb + (size_t)tile * 512);
  };
  auto loadV = [&](int tile) {
    #pragma unroll
    for (int i = 0; i < 4; i++)
      vf[i] = *(const bf16x8*)(vpb + (size_t)tile * 2048 + i * 512);
  };

  const int tb = w * 16;
  loadK(tb); loadV(tb);
  for (int it = 0; it < 16; ++it) {
    const int ti = tb + it;

    // ---- bias + QK^T for both q-tiles (kf, sbias reused 2x) ----
    __builtin_amdgcn_s_setprio(1);
    f32x16 sbias = MFMA32(kbf, QB.v, zv);           // S[kv][q] = bias[kv] (0 / -1e6)
    f32x16 sA = sbias, sB = sbias;
    #pragma unroll
    for (int kk = 0; kk < 4; kk++) sA = MFMA32(kf[kk], qfA[kk], sA);
    #pragma unroll
    for (int kk = 0; kk < 4; kk++) sB = MFMA32(kf[kk], qfB[kk], sB);
    __builtin_amdgcn_s_setprio(0);
    if (it < 15) loadK(ti + 1);          // kf/kbf dead: prefetch under softmax+PV

    // ---- fused online softmax (A and B chains independent) ----
    float tA, tB;
    {
      float a0 = fmaxf(fmaxf(sA[0], sA[1]),  fmaxf(sA[2], sA[3]));
      float a1 = fmaxf(fmaxf(sA[4], sA[5]),  fmaxf(sA[6], sA[7]));
      float a2 = fmaxf(fmaxf(sA[8], sA[9]),  fmaxf(sA[10], sA[11]));
      float a3 = fmaxf(fmaxf(sA[12], sA[13]), fmaxf(sA[14], sA[15]));
      tA = fmaxf(fmaxf(a0, a1), fmaxf(a2, a3));
      float b0 = fmaxf(fmaxf(sB[0], sB[1]),  fmaxf(sB[2], sB[3]));
      float b1 = fmaxf(fmaxf(sB[4], sB[5]),  fmaxf(sB[6], sB[7]));
      float b2 = fmaxf(fmaxf(sB[8], sB[9]),  fmaxf(sB[10], sB[11]));
      float b3 = fmaxf(fmaxf(sB[12], sB[13]), fmaxf(sB[14], sB[15]));
      tB = fmaxf(fmaxf(b0, b1), fmaxf(b2, b3));
    }
    tA = xpair_max(tA);
    tB = xpair_max(tB);
    if (!__all(tA <= mrunA + 400.f)) {              // defer-max: rare
      float mnew = fmaxf(mrunA, tA);
      float sf = fexp2((mrunA - mnew) * C2f);
      lrunA *= sf;
      #pragma unroll
      for (int i = 0; i < 16; i++) { accA0[i] *= sf; accA1[i] *= sf; }
      mrunA = mnew;
    }
    if (!__all(tB <= mrunB + 400.f)) {
      float mnew = fmaxf(mrunB, tB);
      float sf = fexp2((mrunB - mnew) * C2f);
      lrunB *= sf;
      #pragma unroll
      for (int i = 0; i < 16; i++) { accB0[i] *= sf; accB1[i] *= sf; }
      mrunB = mnew;
    }
    float nbA = -mrunA * C2f, nbB = -mrunB * C2f;
    float pA[16], pB[16];
    #pragma unroll
    for (int r = 0; r < 16; r++) pA[r] = fexp2(fmaf(sA[r], C2f, nbA));
    #pragma unroll
    for (int r = 0; r < 16; r++) pB[r] = fexp2(fmaf(sB[r], C2f, nbB));
    lrunA += ((pA[0]+pA[1])+(pA[2]+pA[3])) + ((pA[4]+pA[5])+(pA[6]+pA[7]))
           + ((pA[8]+pA[9])+(pA[10]+pA[11])) + ((pA[12]+pA[13])+(pA[14]+pA[15]));
    lrunB += ((pB[0]+pB[1])+(pB[2]+pB[3])) + ((pB[4]+pB[5])+(pB[6]+pB[7]))
           + ((pB[8]+pB[9])+(pB[10]+pB[11])) + ((pB[12]+pB[13])+(pB[14]+pB[15]));

    unsigned wa[8], wb[8];
    #pragma unroll
    for (int i = 0; i < 8; i++) { wa[i] = cvtpk(pA[2*i], pA[2*i+1]);
                                  wb[i] = cvtpk(pB[2*i], pB[2*i+1]); }
    plswap(wa[0], wa[2]); plswap(wa[1], wa[3]);
    plswap(wa[4], wa[6]); plswap(wa[5], wa[7]);
    plswap(wb[0], wb[2]); plswap(wb[1], wb[3]);
    plswap(wb[4], wb[6]); plswap(wb[5], wb[7]);
    union { unsigned u[4]; bf16x8 v; } UA0, UA1, UB0, UB1;
    UA0.u[0]=wa[0]; UA0.u[1]=wa[1]; UA0.u[2]=wa[2]; UA0.u[3]=wa[3];
    UA1.u[0]=wa[4]; UA1.u[1]=wa[5]; UA1.u[2]=wa[6]; UA1.u[3]=wa[7];
    UB0.u[0]=wb[0]; UB0.u[1]=wb[1]; UB0.u[2]=wb[2]; UB0.u[3]=wb[3];
    UB1.u[0]=wb[4]; UB1.u[1]=wb[5]; UB1.u[2]=wb[6]; UB1.u[3]=wb[7];

    // ---- PV for both q-tiles (vf reused 2x) ----
    __builtin_amdgcn_s_setprio(1);
    accA0 = MFMA32(vf[0], UA0.v, accA0);
    accA0 = MFMA32(vf[1], UA1.v, accA0);
    accA1 = MFMA32(vf[2], UA0.v, accA1);
    accA1 = MFMA32(vf[3], UA1.v, accA1);
    accB0 = MFMA32(vf[0], UB0.v, accB0);
    accB0 = MFMA32(vf[1], UB1.v, accB0);
    accB1 = MFMA32(vf[2], UB0.v, accB1);
    accB1 = MFMA32(vf[3], UB1.v, accB1);
    __builtin_amdgcn_s_setprio(0);
    if (it < 15) loadV(ti + 1);          // vf dead: prefetch under next QK+softmax
  }

  // ---- 4-way merge, twice (A then B), reusing mbuf ----
  auto merge_write = [&](f32x16& a0, f32x16& a1, float mr, float lr, int qt) {
    if (w) {
      #pragma unroll
      for (int i = 0; i < 16; i++) { mbuf[w-1][lane][i] = a0[i]; mbuf[w-1][lane][16 + i] = a1[i]; }
      mbuf[w-1][lane][32] = mr; mbuf[w-1][lane][33] = lr;
    }
    __syncthreads();
    if (!w) {
      float mo[3], lo[3];
      #pragma unroll
      for (int wv = 0; wv < 3; wv++) { mo[wv] = mbuf[wv][lane][32]; lo[wv] = mbuf[wv][lane][33]; }
      float mN = fmaxf(fmaxf(mr, mo[0]), fmaxf(mo[1], mo[2]));
      float sf0 = fexp2((mr - mN) * C2f);
      float sfv[3];
      float lsum = lr * sf0;
      #pragma unroll
      for (int wv = 0; wv < 3; wv++) { sfv[wv] = fexp2((mo[wv] - mN) * C2f); lsum += lo[wv] * sfv[wv]; }
      lsum = xpair_sum(lsum);                       // complete row sum across lane pair
      float linv = 1.f / lsum;
      float a2[32];
      #pragma unroll
      for (int i = 0; i < 16; i++) {
        float v0 = a0[i] * sf0, v1 = a1[i] * sf0;
        #pragma unroll
        for (int wv = 0; wv < 3; wv++) {
          v0 += mbuf[wv][lane][i] * sfv[wv];
          v1 += mbuf[wv][lane][16 + i] * sfv[wv];
        }
        a2[i] = v0 * linv;
        a2[16 + i] = v1 * linv;
      }
      // transpose O^T[d][q] -> O[q][d] via LDS (stride 72 shorts, 16B-aligned rows)
      unsigned short* ot = (unsigned short*)&mbuf[0][0][0];
      #pragma unroll
      for (int d2 = 0; d2 < 2; d2++)
        #pragma unroll
        for (int i = 0; i < 8; i++) {
          int d0 = ((2 * i) & 3) + 8 * (i >> 1) + 4 * hi + 32 * d2;
          unsigned wv2 = cvtpk(a2[d2 * 16 + 2 * i], a2[d2 * 16 + 2 * i + 1]);
          *(unsigned*)(ot + q5 * 72 + d0) = wv2;
        }
      #pragma unroll
      for (int it2 = 0; it2 < 4; ++it2) {
        int row = (lane >> 3) + it2 * 8, ch = lane & 7;
        uint4 val = *(const uint4*)(ot + row * 72 + ch * 8);
        *(uint4*)(O + ((size_t)(b * 2048 + qt * 32 + row)) * 512 + h * 64 + ch * 8) = val;
      }
    }
    __syncthreads();                                // mbuf free for next pass
  };
  merge_write(accA0, accA1, mrunA, lrunA, qtA);
  merge_write(accB0, accB1, mrunB, lrunB, qtB);
}

// ---------------- host ----------------
extern "C" void kernel_launch(void* const* d_in, const int* in_sizes, int n_in,
                              void* d_out, int out_size, void* d_ws, size_t ws_size,
                              hipStream_t stream) {
  const float* x     = (const float*)d_in[0];
  const float* ctx   = (const float*)d_in[1];
  const int*   mask  = (const int*)d_in[2];
  const float* ln_g  = (const float*)d_in[3];
  const float* ln_b  = (const float*)d_in[4];
  const float* Wq    = (const float*)d_in[5];
  const float* Wkv   = (const float*)d_in[6];
  const float* Wo    = (const float*)d_in[7];
  const float* lno_g = (const float*)d_in[8];
  const float* lno_b = (const float*)d_in[9];
  float* out = (float*)d_out;

  char* ws = (char*)d_ws;
  unsigned short* WqT  = (unsigned short*)(ws + 0);                         // 512 KB
  unsigned short* WkvT = (unsigned short*)(ws + (size_t)1 * (1 << 19));     // 1 MB
  unsigned short* WoT  = (unsigned short*)(ws + (size_t)3 * (1 << 19));     // 512 KB
  unsigned short* xn   = (unsigned short*)(ws + (size_t)2  * (1 << 20));    // 4 MB
  unsigned short* cb   = (unsigned short*)(ws + (size_t)6  * (1 << 20));    // 4 MB
  unsigned short* Qp   = (unsigned short*)(ws + (size_t)10 * (1 << 20));    // 4 MB (fragment-packed)
  unsigned short* Kp   = (unsigned short*)(ws + (size_t)14 * (1 << 20));    // 4 MB (fragment-packed)
  unsigned short* Vp   = (unsigned short*)(ws + (size_t)18 * (1 << 20));    // 4 MB (fragment-packed)
  unsigned short* ao   = (unsigned short*)(ws + (size_t)22 * (1 << 20));    // 4 MB
  float* proj          = (float*)(ws + (size_t)26 * (1 << 20));             // 8 MB
  unsigned short* kbias = (unsigned short*)(ws + (size_t)26 * (1 << 20));   // 128 KB, overlaps proj (dead by then)

  k_prep<<<4112, 256, 0, stream>>>(Wq, Wkv, Wo, x, ln_g, ln_b, ctx, mask,
                                   WqT, WkvT, WoT, xn, cb, kbias);
  k_qkv<<<768, 256, 0, stream>>>(xn, WqT, Qp, cb, WkvT, Kp, Vp);
  k_attn<<<512, 256, 0, stream>>>(Qp, Kp, Vp, kbias, ao);
  k_oproj<<<256, 256, 0, stream>>>(ao, WoT, proj);
  k_layernorm_f<<<1024, 256, 0, stream>>>(proj, lno_g, lno_b, out);
}